// Round 1
// baseline (1339.447 us; speedup 1.0000x reference)
//
#include <hip/hip_runtime.h>
#include <cstdint>
#include <cstddef>

#define F_IN 1024
#define F1 64
#define H1 8
#define C1 8
#define C_OUT 40
#define NEG 0.2f

static __device__ __forceinline__ float lrelu(float a) { return a > 0.f ? a : NEG * a; }

// ---------- GEMM1: xw1[n,64] = x[n,1024] @ W1[1024,64] ----------
__global__ __launch_bounds__(256) void gemm1_kernel(const float* __restrict__ x,
                                                    const float* __restrict__ W,
                                                    float* __restrict__ xw, int n) {
  __shared__ float xs[64][68];   // +4 pad: kills bank conflicts on column reads
  __shared__ float ws[64][64];
  const int tid = threadIdx.x;
  const int n0 = blockIdx.x * 64;
  const int tx = tid & 15, ty = tid >> 4;
  float4 a0 = {0,0,0,0}, a1 = {0,0,0,0}, a2 = {0,0,0,0}, a3 = {0,0,0,0};
  for (int kb = 0; kb < F_IN; kb += 64) {
#pragma unroll
    for (int i = 0; i < 4; ++i) {
      int li = tid + i * 256;       // 0..1023 float4 slots
      int r = li >> 4;              // 0..63
      int c = (li & 15) << 2;       // 0..60
      int gr = n0 + r;
      float4 v = make_float4(0.f, 0.f, 0.f, 0.f);
      if (gr < n) v = *(const float4*)(x + (size_t)gr * F_IN + kb + c);
      *(float4*)&xs[r][c] = v;
      *(float4*)&ws[r][c] = *(const float4*)(W + (size_t)(kb + r) * F1 + c);
    }
    __syncthreads();
#pragma unroll 8
    for (int kk = 0; kk < 64; ++kk) {
      float4 wv = *(const float4*)&ws[kk][tx << 2];
      float x0 = xs[ty * 4 + 0][kk], x1 = xs[ty * 4 + 1][kk];
      float x2 = xs[ty * 4 + 2][kk], x3 = xs[ty * 4 + 3][kk];
      a0.x += x0 * wv.x; a0.y += x0 * wv.y; a0.z += x0 * wv.z; a0.w += x0 * wv.w;
      a1.x += x1 * wv.x; a1.y += x1 * wv.y; a1.z += x1 * wv.z; a1.w += x1 * wv.w;
      a2.x += x2 * wv.x; a2.y += x2 * wv.y; a2.z += x2 * wv.z; a2.w += x2 * wv.w;
      a3.x += x3 * wv.x; a3.y += x3 * wv.y; a3.z += x3 * wv.z; a3.w += x3 * wv.w;
    }
    __syncthreads();
  }
  float4 accs[4] = {a0, a1, a2, a3};
#pragma unroll
  for (int i = 0; i < 4; ++i) {
    int gr = n0 + ty * 4 + i;
    if (gr < n) *(float4*)(xw + (size_t)gr * F1 + (tx << 2)) = accs[i];
  }
}

// ---------- per-(node,head) attention logits, layer 1 ----------
__global__ __launch_bounds__(256) void al1_kernel(const float* __restrict__ xw1,
    const float* __restrict__ asrc, const float* __restrict__ adst,
    float* __restrict__ al_src, float* __restrict__ al_dst, int n) {
  int id = blockIdx.x * 256 + threadIdx.x;
  if (id >= n * H1) return;
  int node = id >> 3, h = id & 7;
  const float* row = xw1 + (size_t)node * F1 + h * C1;
  float s = 0.f, d = 0.f;
#pragma unroll
  for (int c = 0; c < C1; ++c) {
    float v = row[c];
    s += v * asrc[h * C1 + c];
    d += v * adst[h * C1 + c];
  }
  al_src[id] = s;
  al_dst[id] = d;
}

// ---------- CSR build ----------
__global__ __launch_bounds__(256) void hist_kernel(const int* __restrict__ dst,
                                                   int* __restrict__ deg, int e) {
  int i = blockIdx.x * 256 + threadIdx.x;
  if (i < e) atomicAdd(&deg[dst[i]], 1);
}

__global__ __launch_bounds__(256) void scan1_kernel(const int* __restrict__ deg,
    int* __restrict__ excl, int* __restrict__ bsum, int n) {
  __shared__ int s[256];
  int tid = threadIdx.x;
  int gid = blockIdx.x * 256 + tid;
  int v = gid < n ? deg[gid] : 0;
  s[tid] = v;
  __syncthreads();
  for (int ofs = 1; ofs < 256; ofs <<= 1) {
    int t = (tid >= ofs) ? s[tid - ofs] : 0;
    __syncthreads();
    s[tid] += t;
    __syncthreads();
  }
  if (gid < n) excl[gid] = s[tid] - v;
  if (tid == 255) bsum[blockIdx.x] = s[255];
}

__global__ __launch_bounds__(1024) void scan2_kernel(int* __restrict__ bsum, int nb) {
  __shared__ int s[1024];
  int tid = threadIdx.x;
  int v = tid < nb ? bsum[tid] : 0;
  s[tid] = v;
  __syncthreads();
  for (int ofs = 1; ofs < 1024; ofs <<= 1) {
    int t = (tid >= ofs) ? s[tid - ofs] : 0;
    __syncthreads();
    s[tid] += t;
    __syncthreads();
  }
  if (tid < nb) bsum[tid] = s[tid] - v;  // exclusive
}

__global__ __launch_bounds__(256) void scan3_kernel(int* __restrict__ off,
    const int* __restrict__ bsumx, int* __restrict__ cur, int n) {
  int gid = blockIdx.x * 256 + threadIdx.x;
  if (gid < n) {
    int o = off[gid] + bsumx[blockIdx.x];
    off[gid] = o;
    cur[gid] = o;
  }
}

__global__ __launch_bounds__(256) void fill_kernel(const int* __restrict__ src,
    const int* __restrict__ dst, int* __restrict__ cur, int* __restrict__ csr, int e) {
  int i = blockIdx.x * 256 + threadIdx.x;
  if (i < e) {
    int d = dst[i];
    int pos = atomicAdd(&cur[d], 1);
    csr[pos] = src[i];
  }
}

// ---------- layer-1 aggregation: wave per node, 8 heads x 8 ch ----------
__global__ __launch_bounds__(256) void gat1_agg(const float* __restrict__ xw1,
    const float* __restrict__ al_src, const float* __restrict__ al_dst,
    const int* __restrict__ csr, const int* __restrict__ off, const int* __restrict__ deg,
    const float* __restrict__ b1, float* __restrict__ h1, int n) {
  int wid = (blockIdx.x * blockDim.x + threadIdx.x) >> 6;
  int lane = threadIdx.x & 63;
  if (wid >= n) return;
  const int node = wid;
  const int base = off[node], cnt = deg[node];

  // ---- pass A: online (m,l) per head; lane = e8*8 + h ----
  const int h = lane & 7;
  const float adst = al_dst[node * H1 + h];
  float m = -1e30f, l = 0.f;
  for (int it = lane >> 3; it < cnt; it += 8) {
    int s = csr[base + it];
    float sc = lrelu(al_src[s * H1 + h] + adst);
    float nm = fmaxf(m, sc);
    l = l * __expf(m - nm) + __expf(sc - nm);
    m = nm;
  }
#pragma unroll
  for (int mask = 8; mask <= 32; mask <<= 1) {
    float om = __shfl_xor(m, mask), ol = __shfl_xor(l, mask);
    float nm = fmaxf(m, om);
    l = l * __expf(m - nm) + ol * __expf(om - nm);
    m = nm;
  }
  // merge self-loop (score uses node's own src+dst logits)
  const float sc_self = lrelu(al_src[node * H1 + h] + adst);
  {
    float nm = fmaxf(m, sc_self);
    l = l * __expf(m - nm) + __expf(sc_self - nm);
    m = nm;
  }

  // ---- pass B: lane = h2*8 + c ; fetch (m,l) for h2 from lane h2 ----
  const int h2 = lane >> 3;
  const float mj = __shfl(m, h2);
  const float lj = __shfl(l, h2);
  const float adst2 = al_dst[node * H1 + h2];
  float acc = 0.f;
  for (int it = 0; it < cnt; ++it) {
    int s = csr[base + it];
    float sc = lrelu(al_src[s * H1 + h2] + adst2);
    float p = __expf(sc - mj);
    acc += p * xw1[(size_t)s * F1 + lane];
  }
  {
    float sc = lrelu(al_src[node * H1 + h2] + adst2);
    acc += __expf(sc - mj) * xw1[(size_t)node * F1 + lane];
  }
  float outv = acc / (lj + 1e-16f) + b1[lane];
  h1[(size_t)node * F1 + lane] = outv > 0.f ? outv : __expf(outv) - 1.f;  // ELU
}

// ---------- GEMM2: xw2[n,40] = h1[n,64] @ W2[64,40] ----------
__global__ __launch_bounds__(256) void gemm2_kernel(const float* __restrict__ h1,
    const float* __restrict__ W2, float* __restrict__ xw2, int n) {
  __shared__ float ws[F1 * C_OUT];
  int tid = threadIdx.x;
  for (int i = tid; i < F1 * C_OUT; i += 256) ws[i] = W2[i];
  __syncthreads();
  int node = blockIdx.x * 32 + (tid >> 3);
  int j = tid & 7;
  if (node >= n) return;
  const float* row = h1 + (size_t)node * F1;
  float acc[5] = {0.f, 0.f, 0.f, 0.f, 0.f};
  for (int k = 0; k < F1; ++k) {
    float xv = row[k];
#pragma unroll
    for (int i = 0; i < 5; ++i) acc[i] += xv * ws[k * C_OUT + j + 8 * i];
  }
#pragma unroll
  for (int i = 0; i < 5; ++i) xw2[(size_t)node * C_OUT + j + 8 * i] = acc[i];
}

// ---------- per-node attention logits, layer 2 (1 head, 40 ch) ----------
__global__ __launch_bounds__(256) void al2_kernel(const float* __restrict__ xw2,
    const float* __restrict__ asrc, const float* __restrict__ adst,
    float* __restrict__ al_src, float* __restrict__ al_dst, int n) {
  __shared__ float sa[C_OUT], sd[C_OUT];
  if (threadIdx.x < C_OUT) {
    sa[threadIdx.x] = asrc[threadIdx.x];
    sd[threadIdx.x] = adst[threadIdx.x];
  }
  __syncthreads();
  int node = blockIdx.x * 256 + threadIdx.x;
  if (node >= n) return;
  const float* row = xw2 + (size_t)node * C_OUT;
  float s = 0.f, d = 0.f;
#pragma unroll
  for (int c = 0; c < C_OUT; ++c) {
    float v = row[c];
    s += v * sa[c];
    d += v * sd[c];
  }
  al_src[node] = s;
  al_dst[node] = d;
}

// ---------- layer-2 aggregation + log_softmax: wave per node ----------
__global__ __launch_bounds__(256) void gat2_agg(const float* __restrict__ xw2,
    const float* __restrict__ al_src, const float* __restrict__ al_dst,
    const int* __restrict__ csr, const int* __restrict__ off, const int* __restrict__ deg,
    const float* __restrict__ b2, float* __restrict__ out, int n) {
  int wid = (blockIdx.x * blockDim.x + threadIdx.x) >> 6;
  int lane = threadIdx.x & 63;
  if (wid >= n) return;
  const int node = wid;
  const int base = off[node], cnt = deg[node];
  const float adst = al_dst[node];

  // pass A: online (m,l), each lane strided over edges
  float m = -1e30f, l = 0.f;
  for (int it = lane; it < cnt; it += 64) {
    int s = csr[base + it];
    float sc = lrelu(al_src[s] + adst);
    float nm = fmaxf(m, sc);
    l = l * __expf(m - nm) + __expf(sc - nm);
    m = nm;
  }
#pragma unroll
  for (int mask = 1; mask <= 32; mask <<= 1) {
    float om = __shfl_xor(m, mask), ol = __shfl_xor(l, mask);
    float nm = fmaxf(m, om);
    l = l * __expf(m - nm) + ol * __expf(om - nm);
    m = nm;
  }
  const float sc_self = lrelu(al_src[node] + adst);
  {
    float nm = fmaxf(m, sc_self);
    l = l * __expf(m - nm) + __expf(sc_self - nm);
    m = nm;
  }

  // pass B: lanes 0..39 accumulate the 40 output channels
  float acc = 0.f;
  for (int it = 0; it < cnt; ++it) {
    int s = csr[base + it];
    float sc = lrelu(al_src[s] + adst);
    float p = __expf(sc - m);
    if (lane < C_OUT) acc += p * xw2[(size_t)s * C_OUT + lane];
  }
  if (lane < C_OUT) acc += __expf(sc_self - m) * xw2[(size_t)node * C_OUT + lane];

  float val = (lane < C_OUT) ? acc / (l + 1e-16f) + b2[lane] : -1e30f;
  // log_softmax across the 40 lanes
  float mx = val;
#pragma unroll
  for (int mask = 1; mask <= 32; mask <<= 1) mx = fmaxf(mx, __shfl_xor(mx, mask));
  float ex = (lane < C_OUT) ? __expf(val - mx) : 0.f;
  float sum = ex;
#pragma unroll
  for (int mask = 1; mask <= 32; mask <<= 1) sum += __shfl_xor(sum, mask);
  if (lane < C_OUT) out[(size_t)node * C_OUT + lane] = val - mx - __logf(sum);
}

extern "C" void kernel_launch(void* const* d_in, const int* in_sizes, int n_in,
                              void* d_out, int out_size, void* d_ws, size_t ws_size,
                              hipStream_t stream) {
  const float* x   = (const float*)d_in[0];
  const int*   ei  = (const int*)d_in[1];
  const float* W1  = (const float*)d_in[2];
  const float* as1 = (const float*)d_in[3];
  const float* ad1 = (const float*)d_in[4];
  const float* b1  = (const float*)d_in[5];
  const float* W2  = (const float*)d_in[6];
  const float* as2 = (const float*)d_in[7];
  const float* ad2 = (const float*)d_in[8];
  const float* b2  = (const float*)d_in[9];
  float* out = (float*)d_out;

  const int n = in_sizes[0] / F_IN;
  const int e = in_sizes[1] / 2;
  const int* srcIdx = ei;
  const int* dstIdx = ei + e;

  char* p = (char*)d_ws;
  auto take = [&](size_t bytes) {
    char* q = p;
    p += (bytes + 255) & ~(size_t)255;
    return q;
  };
  float* xw1  = (float*)take((size_t)n * F1 * 4);
  float* h1   = (float*)take((size_t)n * F1 * 4);
  float* xw2  = (float*)take((size_t)n * C_OUT * 4);
  float* alS1 = (float*)take((size_t)n * H1 * 4);
  float* alD1 = (float*)take((size_t)n * H1 * 4);
  float* alS2 = (float*)take((size_t)n * 4);
  float* alD2 = (float*)take((size_t)n * 4);
  int* deg  = (int*)take((size_t)n * 4);
  int* offb = (int*)take((size_t)n * 4);
  int* cur  = (int*)take((size_t)n * 4);
  int* bsum = (int*)take(4096);
  int* csr  = (int*)take((size_t)e * 4);

  hipMemsetAsync(deg, 0, (size_t)n * 4, stream);

  dim3 b256(256);
  gemm1_kernel<<<dim3((n + 63) / 64), b256, 0, stream>>>(x, W1, xw1, n);
  al1_kernel<<<dim3((n * H1 + 255) / 256), b256, 0, stream>>>(xw1, as1, ad1, alS1, alD1, n);
  hist_kernel<<<dim3((e + 255) / 256), b256, 0, stream>>>(dstIdx, deg, e);
  int nb1 = (n + 255) / 256;
  scan1_kernel<<<dim3(nb1), b256, 0, stream>>>(deg, offb, bsum, n);
  scan2_kernel<<<dim3(1), dim3(1024), 0, stream>>>(bsum, nb1);
  scan3_kernel<<<dim3(nb1), b256, 0, stream>>>(offb, bsum, cur, n);
  fill_kernel<<<dim3((e + 255) / 256), b256, 0, stream>>>(srcIdx, dstIdx, cur, csr, e);
  gat1_agg<<<dim3((n + 3) / 4), b256, 0, stream>>>(xw1, alS1, alD1, csr, offb, deg, b1, h1, n);
  gemm2_kernel<<<dim3((n + 31) / 32), b256, 0, stream>>>(h1, W2, xw2, n);
  al2_kernel<<<dim3((n + 255) / 256), b256, 0, stream>>>(xw2, as2, ad2, alS2, alD2, n);
  gat2_agg<<<dim3((n + 3) / 4), b256, 0, stream>>>(xw2, alS2, alD2, csr, offb, deg, b2, out, n);
}

// Round 2
// 1022.368 us; speedup vs baseline: 1.3101x; 1.3101x over previous
//
#include <hip/hip_runtime.h>
#include <cstdint>
#include <cstddef>

#define F_IN 1024
#define F1 64
#define H1 8
#define C1 8
#define C_OUT 40
#define NEG 0.2f

static __device__ __forceinline__ float lrelu(float a) { return a > 0.f ? a : NEG * a; }

static __device__ __forceinline__ unsigned short f2bf(float f) {
  union { float f; unsigned u; } v; v.f = f;
  unsigned r = v.u + 0x7fff + ((v.u >> 16) & 1);  // RNE
  return (unsigned short)(r >> 16);
}
static __device__ __forceinline__ float bf2f(unsigned short h) {
  union { unsigned u; float f; } v; v.u = ((unsigned)h) << 16; return v.f;
}

// ---------- GEMM1: xw1[n,64] = x[n,1024] @ W1[1024,64], bf16 out ----------
__global__ __launch_bounds__(256) void gemm1_kernel(const float* __restrict__ x,
                                                    const float* __restrict__ W,
                                                    unsigned short* __restrict__ xwbf,
                                                    int n) {
  __shared__ float xs[64][68];   // TRANSPOSED: xs[k][row]; pad keeps 16B align + banks
  __shared__ float ws[64][68];   // ws[k][col]
  const int tid = threadIdx.x;
  const int n0 = blockIdx.x * 64;
  const int tx = tid & 15, ty = tid >> 4;
  float4 a0 = {0,0,0,0}, a1 = {0,0,0,0}, a2 = {0,0,0,0}, a3 = {0,0,0,0};
  for (int kb = 0; kb < F_IN; kb += 64) {
#pragma unroll
    for (int i = 0; i < 4; ++i) {
      int li = tid + i * 256;       // 0..1023 float4 slots
      int r = li >> 4;              // 0..63
      int c = (li & 15) << 2;       // 0..60
      int gr = n0 + r;
      float4 v = make_float4(0.f, 0.f, 0.f, 0.f);
      if (gr < n) v = *(const float4*)(x + (size_t)gr * F_IN + kb + c);
      xs[c + 0][r] = v.x; xs[c + 1][r] = v.y; xs[c + 2][r] = v.z; xs[c + 3][r] = v.w;
      *(float4*)&ws[r][c] = *(const float4*)(W + (size_t)(kb + r) * F1 + c);
    }
    __syncthreads();
#pragma unroll 8
    for (int kk = 0; kk < 64; ++kk) {
      float4 xv = *(const float4*)&xs[kk][ty << 2];
      float4 wv = *(const float4*)&ws[kk][tx << 2];
      a0.x += xv.x * wv.x; a0.y += xv.x * wv.y; a0.z += xv.x * wv.z; a0.w += xv.x * wv.w;
      a1.x += xv.y * wv.x; a1.y += xv.y * wv.y; a1.z += xv.y * wv.z; a1.w += xv.y * wv.w;
      a2.x += xv.z * wv.x; a2.y += xv.z * wv.y; a2.z += xv.z * wv.z; a2.w += xv.z * wv.w;
      a3.x += xv.w * wv.x; a3.y += xv.w * wv.y; a3.z += xv.w * wv.z; a3.w += xv.w * wv.w;
    }
    __syncthreads();
  }
  float4 accs[4] = {a0, a1, a2, a3};
#pragma unroll
  for (int i = 0; i < 4; ++i) {
    int gr = n0 + (ty << 2) + i;
    if (gr < n) {
      ushort4 o;
      o.x = f2bf(accs[i].x); o.y = f2bf(accs[i].y);
      o.z = f2bf(accs[i].z); o.w = f2bf(accs[i].w);
      *(ushort4*)(xwbf + (size_t)gr * F1 + (tx << 2)) = o;
    }
  }
}

// ---------- per-(node,head) attention logits, layer 1 ----------
__global__ __launch_bounds__(256) void al1_kernel(const unsigned short* __restrict__ xw1,
    const float* __restrict__ asrc, const float* __restrict__ adst,
    float* __restrict__ al_src, float* __restrict__ al_dst, int n) {
  int id = blockIdx.x * 256 + threadIdx.x;
  if (id >= n * H1) return;
  int node = id >> 3, h = id & 7;
  const unsigned short* row = xw1 + (size_t)node * F1 + h * C1;
  float s = 0.f, d = 0.f;
#pragma unroll
  for (int c = 0; c < C1; ++c) {
    float v = bf2f(row[c]);
    s += v * asrc[h * C1 + c];
    d += v * adst[h * C1 + c];
  }
  al_src[id] = s;
  al_dst[id] = d;
}

// ---------- CSR build ----------
__global__ __launch_bounds__(256) void hist_kernel(const int* __restrict__ dst,
                                                   int* __restrict__ deg, int e) {
  int i = blockIdx.x * 256 + threadIdx.x;
  if (i < e) atomicAdd(&deg[dst[i]], 1);
}

__global__ __launch_bounds__(256) void scan1_kernel(const int* __restrict__ deg,
    int* __restrict__ excl, int* __restrict__ bsum, int n) {
  __shared__ int s[256];
  int tid = threadIdx.x;
  int gid = blockIdx.x * 256 + tid;
  int v = gid < n ? deg[gid] : 0;
  s[tid] = v;
  __syncthreads();
  for (int ofs = 1; ofs < 256; ofs <<= 1) {
    int t = (tid >= ofs) ? s[tid - ofs] : 0;
    __syncthreads();
    s[tid] += t;
    __syncthreads();
  }
  if (gid < n) excl[gid] = s[tid] - v;
  if (tid == 255) bsum[blockIdx.x] = s[255];
}

__global__ __launch_bounds__(1024) void scan2_kernel(int* __restrict__ bsum, int nb) {
  __shared__ int s[1024];
  int tid = threadIdx.x;
  int v = tid < nb ? bsum[tid] : 0;
  s[tid] = v;
  __syncthreads();
  for (int ofs = 1; ofs < 1024; ofs <<= 1) {
    int t = (tid >= ofs) ? s[tid - ofs] : 0;
    __syncthreads();
    s[tid] += t;
    __syncthreads();
  }
  if (tid < nb) bsum[tid] = s[tid] - v;  // exclusive
}

__global__ __launch_bounds__(256) void scan3_kernel(int* __restrict__ off,
    const int* __restrict__ bsumx, int* __restrict__ cur, int n) {
  int gid = blockIdx.x * 256 + threadIdx.x;
  if (gid < n) {
    int o = off[gid] + bsumx[blockIdx.x];
    off[gid] = o;
    cur[gid] = o;
  }
}

__global__ __launch_bounds__(256) void fill_kernel(const int* __restrict__ src,
    const int* __restrict__ dst, int* __restrict__ cur, int* __restrict__ csr, int e) {
  int i = blockIdx.x * 256 + threadIdx.x;
  if (i < e) {
    int d = dst[i];
    int pos = atomicAdd(&cur[d], 1);
    csr[pos] = src[i];
  }
}

// ---------- layer-1 aggregation: wave per node, fused online softmax ----------
__global__ __launch_bounds__(256) void gat1_agg(const unsigned short* __restrict__ xw1,
    const float* __restrict__ al_src, const float* __restrict__ al_dst,
    const int* __restrict__ csr, const int* __restrict__ off, const int* __restrict__ deg,
    const float* __restrict__ b1, float* __restrict__ h1, int n) {
  int wid = (blockIdx.x * blockDim.x + threadIdx.x) >> 6;
  int lane = threadIdx.x & 63;
  if (wid >= n) return;
  const int node = wid;
  const int base = off[node], cnt = deg[node];
  const int h2 = lane >> 3;
  const float adst2 = al_dst[node * H1 + h2];

  float m = -1e30f, l = 0.f, acc = 0.f;

#define ON1(aj, xj) { \
    float sc = lrelu((aj) + adst2); \
    float nm = fmaxf(m, sc); \
    float e1 = __expf(m - nm); \
    float p  = __expf(sc - nm); \
    acc = acc * e1 + p * (xj); \
    l   = l   * e1 + p; \
    m = nm; }

  int it = 0;
  for (; it + 4 <= cnt; it += 4) {
    int s0 = csr[base + it + 0], s1 = csr[base + it + 1];
    int s2 = csr[base + it + 2], s3 = csr[base + it + 3];
    float a0v = al_src[s0 * H1 + h2], a1v = al_src[s1 * H1 + h2];
    float a2v = al_src[s2 * H1 + h2], a3v = al_src[s3 * H1 + h2];
    float x0 = bf2f(xw1[(size_t)s0 * F1 + lane]);
    float x1 = bf2f(xw1[(size_t)s1 * F1 + lane]);
    float x2 = bf2f(xw1[(size_t)s2 * F1 + lane]);
    float x3 = bf2f(xw1[(size_t)s3 * F1 + lane]);
    ON1(a0v, x0); ON1(a1v, x1); ON1(a2v, x2); ON1(a3v, x3);
  }
  for (; it < cnt; ++it) {
    int s = csr[base + it];
    float av = al_src[s * H1 + h2];
    float xv = bf2f(xw1[(size_t)s * F1 + lane]);
    ON1(av, xv);
  }
  // self-loop
  {
    float av = al_src[node * H1 + h2];
    float xv = bf2f(xw1[(size_t)node * F1 + lane]);
    ON1(av, xv);
  }
#undef ON1

  float outv = acc / (l + 1e-16f) + b1[lane];
  h1[(size_t)node * F1 + lane] = outv > 0.f ? outv : __expf(outv) - 1.f;  // ELU
}

// ---------- GEMM2: xw2[n,40] = h1[n,64] @ W2[64,40], bf16 out ----------
__global__ __launch_bounds__(256) void gemm2_kernel(const float* __restrict__ h1,
    const float* __restrict__ W2, unsigned short* __restrict__ xw2, int n) {
  __shared__ float ws[F1 * C_OUT];
  int tid = threadIdx.x;
  for (int i = tid; i < F1 * C_OUT; i += 256) ws[i] = W2[i];
  __syncthreads();
  int node = blockIdx.x * 256 + tid;
  if (node >= n) return;
  const float4* row4 = (const float4*)(h1 + (size_t)node * F1);
  float acc[C_OUT];
#pragma unroll
  for (int j = 0; j < C_OUT; ++j) acc[j] = 0.f;
#pragma unroll 2
  for (int k4 = 0; k4 < 16; ++k4) {
    float4 xv = row4[k4];
    const float* w0 = &ws[(4 * k4 + 0) * C_OUT];
    const float* w1 = &ws[(4 * k4 + 1) * C_OUT];
    const float* w2 = &ws[(4 * k4 + 2) * C_OUT];
    const float* w3 = &ws[(4 * k4 + 3) * C_OUT];
#pragma unroll
    for (int j = 0; j < C_OUT; j += 4) {
      float4 v0 = *(const float4*)(w0 + j);
      float4 v1 = *(const float4*)(w1 + j);
      float4 v2 = *(const float4*)(w2 + j);
      float4 v3 = *(const float4*)(w3 + j);
      acc[j + 0] += xv.x * v0.x + xv.y * v1.x + xv.z * v2.x + xv.w * v3.x;
      acc[j + 1] += xv.x * v0.y + xv.y * v1.y + xv.z * v2.y + xv.w * v3.y;
      acc[j + 2] += xv.x * v0.z + xv.y * v1.z + xv.z * v2.z + xv.w * v3.z;
      acc[j + 3] += xv.x * v0.w + xv.y * v1.w + xv.z * v2.w + xv.w * v3.w;
    }
  }
  unsigned short* orow = xw2 + (size_t)node * C_OUT;
#pragma unroll
  for (int j = 0; j < C_OUT; j += 4) {
    ushort4 o;
    o.x = f2bf(acc[j + 0]); o.y = f2bf(acc[j + 1]);
    o.z = f2bf(acc[j + 2]); o.w = f2bf(acc[j + 3]);
    *(ushort4*)(orow + j) = o;
  }
}

// ---------- per-node attention logits, layer 2 (1 head, 40 ch) ----------
__global__ __launch_bounds__(256) void al2_kernel(const unsigned short* __restrict__ xw2,
    const float* __restrict__ asrc, const float* __restrict__ adst,
    float* __restrict__ al_src, float* __restrict__ al_dst, int n) {
  __shared__ float sa[C_OUT], sd[C_OUT];
  if (threadIdx.x < C_OUT) {
    sa[threadIdx.x] = asrc[threadIdx.x];
    sd[threadIdx.x] = adst[threadIdx.x];
  }
  __syncthreads();
  int node = blockIdx.x * 256 + threadIdx.x;
  if (node >= n) return;
  const unsigned short* row = xw2 + (size_t)node * C_OUT;
  float s = 0.f, d = 0.f;
#pragma unroll
  for (int c = 0; c < C_OUT; ++c) {
    float v = bf2f(row[c]);
    s += v * sa[c];
    d += v * sd[c];
  }
  al_src[node] = s;
  al_dst[node] = d;
}

// ---------- layer-2 aggregation + log_softmax: wave per node, fused ----------
__global__ __launch_bounds__(256) void gat2_agg(const unsigned short* __restrict__ xw2,
    const float* __restrict__ al_src, const float* __restrict__ al_dst,
    const int* __restrict__ csr, const int* __restrict__ off, const int* __restrict__ deg,
    const float* __restrict__ b2, float* __restrict__ out, int n) {
  int wid = (blockIdx.x * blockDim.x + threadIdx.x) >> 6;
  int lane = threadIdx.x & 63;
  if (wid >= n) return;
  const int node = wid;
  const int base = off[node], cnt = deg[node];
  const float adst = al_dst[node];
  const bool act = lane < C_OUT;

  float m = -1e30f, l = 0.f, acc = 0.f;

#define ON2(aj, xj) { \
    float sc = lrelu((aj) + adst); \
    float nm = fmaxf(m, sc); \
    float e1 = __expf(m - nm); \
    float p  = __expf(sc - nm); \
    acc = acc * e1 + p * (xj); \
    l   = l   * e1 + p; \
    m = nm; }

  int it = 0;
  for (; it + 4 <= cnt; it += 4) {
    int s0 = csr[base + it + 0], s1 = csr[base + it + 1];
    int s2 = csr[base + it + 2], s3 = csr[base + it + 3];
    float a0v = al_src[s0], a1v = al_src[s1], a2v = al_src[s2], a3v = al_src[s3];
    float x0 = act ? bf2f(xw2[(size_t)s0 * C_OUT + lane]) : 0.f;
    float x1 = act ? bf2f(xw2[(size_t)s1 * C_OUT + lane]) : 0.f;
    float x2 = act ? bf2f(xw2[(size_t)s2 * C_OUT + lane]) : 0.f;
    float x3 = act ? bf2f(xw2[(size_t)s3 * C_OUT + lane]) : 0.f;
    ON2(a0v, x0); ON2(a1v, x1); ON2(a2v, x2); ON2(a3v, x3);
  }
  for (; it < cnt; ++it) {
    int s = csr[base + it];
    float av = al_src[s];
    float xv = act ? bf2f(xw2[(size_t)s * C_OUT + lane]) : 0.f;
    ON2(av, xv);
  }
  // self-loop
  {
    float av = al_src[node];
    float xv = act ? bf2f(xw2[(size_t)node * C_OUT + lane]) : 0.f;
    ON2(av, xv);
  }
#undef ON2

  float val = act ? acc / (l + 1e-16f) + b2[lane] : -1e30f;
  // log_softmax across the 40 lanes
  float mx = val;
#pragma unroll
  for (int mask = 1; mask <= 32; mask <<= 1) mx = fmaxf(mx, __shfl_xor(mx, mask));
  float ex = act ? __expf(val - mx) : 0.f;
  float sum = ex;
#pragma unroll
  for (int mask = 1; mask <= 32; mask <<= 1) sum += __shfl_xor(sum, mask);
  if (act) out[(size_t)node * C_OUT + lane] = val - mx - __logf(sum);
}

extern "C" void kernel_launch(void* const* d_in, const int* in_sizes, int n_in,
                              void* d_out, int out_size, void* d_ws, size_t ws_size,
                              hipStream_t stream) {
  const float* x   = (const float*)d_in[0];
  const int*   ei  = (const int*)d_in[1];
  const float* W1  = (const float*)d_in[2];
  const float* as1 = (const float*)d_in[3];
  const float* ad1 = (const float*)d_in[4];
  const float* b1  = (const float*)d_in[5];
  const float* W2  = (const float*)d_in[6];
  const float* as2 = (const float*)d_in[7];
  const float* ad2 = (const float*)d_in[8];
  const float* b2  = (const float*)d_in[9];
  float* out = (float*)d_out;

  const int n = in_sizes[0] / F_IN;
  const int e = in_sizes[1] / 2;
  const int* srcIdx = ei;
  const int* dstIdx = ei + e;

  char* p = (char*)d_ws;
  auto take = [&](size_t bytes) {
    char* q = p;
    p += (bytes + 255) & ~(size_t)255;
    return q;
  };
  unsigned short* xw1 = (unsigned short*)take((size_t)n * F1 * 2);
  float* h1           = (float*)take((size_t)n * F1 * 4);
  unsigned short* xw2 = (unsigned short*)take((size_t)n * C_OUT * 2);
  float* alS1 = (float*)take((size_t)n * H1 * 4);
  float* alD1 = (float*)take((size_t)n * H1 * 4);
  float* alS2 = (float*)take((size_t)n * 4);
  float* alD2 = (float*)take((size_t)n * 4);
  int* deg  = (int*)take((size_t)n * 4);
  int* offb = (int*)take((size_t)n * 4);
  int* cur  = (int*)take((size_t)n * 4);
  int* bsum = (int*)take(4096);
  int* csr  = (int*)take((size_t)e * 4);

  hipMemsetAsync(deg, 0, (size_t)n * 4, stream);

  dim3 b256(256);
  gemm1_kernel<<<dim3((n + 63) / 64), b256, 0, stream>>>(x, W1, xw1, n);
  al1_kernel<<<dim3((n * H1 + 255) / 256), b256, 0, stream>>>(xw1, as1, ad1, alS1, alD1, n);
  hist_kernel<<<dim3((e + 255) / 256), b256, 0, stream>>>(dstIdx, deg, e);
  int nb1 = (n + 255) / 256;
  scan1_kernel<<<dim3(nb1), b256, 0, stream>>>(deg, offb, bsum, n);
  scan2_kernel<<<dim3(1), dim3(1024), 0, stream>>>(bsum, nb1);
  scan3_kernel<<<dim3(nb1), b256, 0, stream>>>(offb, bsum, cur, n);
  fill_kernel<<<dim3((e + 255) / 256), b256, 0, stream>>>(srcIdx, dstIdx, cur, csr, e);
  gat1_agg<<<dim3((n + 3) / 4), b256, 0, stream>>>(xw1, alS1, alD1, csr, offb, deg, b1, h1, n);
  gemm2_kernel<<<dim3((n + 255) / 256), b256, 0, stream>>>(h1, W2, xw2, n);
  al2_kernel<<<dim3((n + 255) / 256), b256, 0, stream>>>(xw2, as2, ad2, alS2, alD2, n);
  gat2_agg<<<dim3((n + 3) / 4), b256, 0, stream>>>(xw2, alS2, alD2, csr, offb, deg, b2, out, n);
}

// Round 3
// 742.936 us; speedup vs baseline: 1.8029x; 1.3761x over previous
//
#include <hip/hip_runtime.h>
#include <cstdint>
#include <cstddef>

#define F_IN 1024
#define F1 64
#define H1 8
#define C1 8
#define C_OUT 40
#define NEG 0.2f
#define B1 256          // blocks in bin/scatter phase
#define BSHIFT 9        // bucket = dst >> 9 (512 nodes per bucket)
#define BNODES 512

static __device__ __forceinline__ float lrelu(float a) { return a > 0.f ? a : NEG * a; }

static __device__ __forceinline__ unsigned short f2bf(float f) {
  union { float f; unsigned u; } v; v.f = f;
  unsigned r = v.u + 0x7fff + ((v.u >> 16) & 1);  // RNE
  return (unsigned short)(r >> 16);
}
static __device__ __forceinline__ float bf2f(unsigned short h) {
  union { unsigned u; float f; } v; v.u = ((unsigned)h) << 16; return v.f;
}

// ---------- GEMM1: xw1[n,64] = x[n,1024] @ W1[1024,64], bf16 out ----------
__global__ __launch_bounds__(256) void gemm1_kernel(const float* __restrict__ x,
                                                    const float* __restrict__ W,
                                                    unsigned short* __restrict__ xwbf,
                                                    int n) {
  __shared__ float xs[64][68];   // TRANSPOSED: xs[k][row]
  __shared__ float ws[64][68];   // ws[k][col]
  const int tid = threadIdx.x;
  const int n0 = blockIdx.x * 64;
  const int tx = tid & 15, ty = tid >> 4;
  float4 a0 = {0,0,0,0}, a1 = {0,0,0,0}, a2 = {0,0,0,0}, a3 = {0,0,0,0};
  for (int kb = 0; kb < F_IN; kb += 64) {
#pragma unroll
    for (int i = 0; i < 4; ++i) {
      int li = tid + i * 256;
      int r = li >> 4;
      int c = (li & 15) << 2;
      int gr = n0 + r;
      float4 v = make_float4(0.f, 0.f, 0.f, 0.f);
      if (gr < n) v = *(const float4*)(x + (size_t)gr * F_IN + kb + c);
      xs[c + 0][r] = v.x; xs[c + 1][r] = v.y; xs[c + 2][r] = v.z; xs[c + 3][r] = v.w;
      *(float4*)&ws[r][c] = *(const float4*)(W + (size_t)(kb + r) * F1 + c);
    }
    __syncthreads();
#pragma unroll 8
    for (int kk = 0; kk < 64; ++kk) {
      float4 xv = *(const float4*)&xs[kk][ty << 2];
      float4 wv = *(const float4*)&ws[kk][tx << 2];
      a0.x += xv.x * wv.x; a0.y += xv.x * wv.y; a0.z += xv.x * wv.z; a0.w += xv.x * wv.w;
      a1.x += xv.y * wv.x; a1.y += xv.y * wv.y; a1.z += xv.y * wv.z; a1.w += xv.y * wv.w;
      a2.x += xv.z * wv.x; a2.y += xv.z * wv.y; a2.z += xv.z * wv.z; a2.w += xv.z * wv.w;
      a3.x += xv.w * wv.x; a3.y += xv.w * wv.y; a3.z += xv.w * wv.z; a3.w += xv.w * wv.w;
    }
    __syncthreads();
  }
  float4 accs[4] = {a0, a1, a2, a3};
#pragma unroll
  for (int i = 0; i < 4; ++i) {
    int gr = n0 + (ty << 2) + i;
    if (gr < n) {
      ushort4 o;
      o.x = f2bf(accs[i].x); o.y = f2bf(accs[i].y);
      o.z = f2bf(accs[i].z); o.w = f2bf(accs[i].w);
      *(ushort4*)(xwbf + (size_t)gr * F1 + (tx << 2)) = o;
    }
  }
}

// ---------- per-(node,head) attention logits, layer 1 ----------
__global__ __launch_bounds__(256) void al1_kernel(const unsigned short* __restrict__ xw1,
    const float* __restrict__ asrc, const float* __restrict__ adst,
    float* __restrict__ al_src, float* __restrict__ al_dst, int n) {
  int id = blockIdx.x * 256 + threadIdx.x;
  if (id >= n * H1) return;
  int node = id >> 3, h = id & 7;
  const unsigned short* row = xw1 + (size_t)node * F1 + h * C1;
  float s = 0.f, d = 0.f;
#pragma unroll
  for (int c = 0; c < C1; ++c) {
    float v = bf2f(row[c]);
    s += v * asrc[h * C1 + c];
    d += v * adst[h * C1 + c];
  }
  al_src[id] = s;
  al_dst[id] = d;
}

// ---------- CSR build via 2-level counting sort ----------
// phase 1: per-(bucket,block) histogram, bucket-major layout
__global__ __launch_bounds__(256) void binhist_kernel(const int* __restrict__ dst,
    int* __restrict__ cnt, int e, int nbuck) {
  __shared__ int lh[256];
  int tid = threadIdx.x, blk = blockIdx.x;
  lh[tid] = 0;
  __syncthreads();
  int chunk = (e + gridDim.x - 1) / gridDim.x;
  int s = blk * chunk, en = min(e, s + chunk);
  for (int i = s + tid; i < en; i += 256) atomicAdd(&lh[dst[i] >> BSHIFT], 1);
  __syncthreads();
  if (tid < nbuck) cnt[tid * B1 + blk] = lh[tid];
}

// scan1/2/3 over the flat cnt array (len = nbuck*B1)
__global__ __launch_bounds__(256) void scan1_kernel(const int* __restrict__ in,
    int* __restrict__ excl, int* __restrict__ bsum, int len) {
  __shared__ int s[256];
  int tid = threadIdx.x;
  int gid = blockIdx.x * 256 + tid;
  int v = gid < len ? in[gid] : 0;
  s[tid] = v;
  __syncthreads();
  for (int ofs = 1; ofs < 256; ofs <<= 1) {
    int t = (tid >= ofs) ? s[tid - ofs] : 0;
    __syncthreads();
    s[tid] += t;
    __syncthreads();
  }
  if (gid < len) excl[gid] = s[tid] - v;
  if (tid == 255) bsum[blockIdx.x] = s[255];
}

__global__ __launch_bounds__(1024) void scan2_kernel(int* __restrict__ bsum, int nb) {
  __shared__ int s[1024];
  int tid = threadIdx.x;
  int v = tid < nb ? bsum[tid] : 0;
  s[tid] = v;
  __syncthreads();
  for (int ofs = 1; ofs < 1024; ofs <<= 1) {
    int t = (tid >= ofs) ? s[tid - ofs] : 0;
    __syncthreads();
    s[tid] += t;
    __syncthreads();
  }
  if (tid < nb) bsum[tid] = s[tid] - v;  // exclusive
}

__global__ __launch_bounds__(256) void scan3_kernel(int* __restrict__ arr,
    const int* __restrict__ bsumx, int len) {
  int gid = blockIdx.x * 256 + threadIdx.x;
  if (gid < len) arr[gid] += bsumx[blockIdx.x];
}

// phase 2: scatter edges into bucket-contiguous runs (LDS cursors, no global atomics)
__global__ __launch_bounds__(256) void binscatter_kernel(const int* __restrict__ src,
    const int* __restrict__ dst, const int* __restrict__ cntS,
    unsigned* __restrict__ binned, int e, int nbuck) {
  __shared__ int lcur[256];
  int tid = threadIdx.x, blk = blockIdx.x;
  if (tid < nbuck) lcur[tid] = cntS[tid * B1 + blk];
  __syncthreads();
  int chunk = (e + gridDim.x - 1) / gridDim.x;
  int s = blk * chunk, en = min(e, s + chunk);
  for (int i = s + tid; i < en; i += 256) {
    int d = dst[i];
    int pos = atomicAdd(&lcur[d >> BSHIFT], 1);
    binned[pos] = ((unsigned)(d & (BNODES - 1)) << 23) | (unsigned)src[i];
  }
}

// phase 3: per-bucket counting sort -> deg, off, csr
__global__ __launch_bounds__(256) void bucket_csr_kernel(const unsigned* __restrict__ binned,
    const int* __restrict__ cntS, int* __restrict__ deg, int* __restrict__ off,
    int* __restrict__ csr, int e, int n, int nbuck) {
  int q = blockIdx.x, tid = threadIdx.x;
  int eBase = cntS[q * B1];
  int eEnd = (q + 1 < nbuck) ? cntS[(q + 1) * B1] : e;
  __shared__ int nh[BNODES], sc[BNODES], cu[BNODES];
  nh[tid] = 0; nh[tid + 256] = 0;
  __syncthreads();
  for (int i = eBase + tid; i < eEnd; i += 256) atomicAdd(&nh[binned[i] >> 23], 1);
  __syncthreads();
  sc[tid] = nh[tid]; sc[tid + 256] = nh[tid + 256];
  __syncthreads();
  for (int ofs = 1; ofs < BNODES; ofs <<= 1) {
    int a0 = sc[tid], a1 = sc[tid + 256];
    int b0 = (tid >= ofs) ? sc[tid - ofs] : 0;
    int b1 = (tid + 256 >= ofs) ? sc[tid + 256 - ofs] : 0;
    __syncthreads();
    sc[tid] = a0 + b0; sc[tid + 256] = a1 + b1;
    __syncthreads();
  }
  int e0 = sc[tid] - nh[tid], e1 = sc[tid + 256] - nh[tid + 256];
  cu[tid] = e0; cu[tid + 256] = e1;
  int node0 = q * BNODES + tid, node1 = node0 + 256;
  if (node0 < n) { deg[node0] = nh[tid];       off[node0] = eBase + e0; }
  if (node1 < n) { deg[node1] = nh[tid + 256]; off[node1] = eBase + e1; }
  __syncthreads();
  for (int i = eBase + tid; i < eEnd; i += 256) {
    unsigned v = binned[i];
    int pos = eBase + atomicAdd(&cu[v >> 23], 1);
    csr[pos] = (int)(v & 0x7FFFFF);
  }
}

// ---------- layer-1 aggregation: wave per node, fused online softmax ----------
__global__ __launch_bounds__(256) void gat1_agg(const unsigned short* __restrict__ xw1,
    const float* __restrict__ al_src, const float* __restrict__ al_dst,
    const int* __restrict__ csr, const int* __restrict__ off, const int* __restrict__ deg,
    const float* __restrict__ b1, float* __restrict__ h1, int n) {
  int wid = (blockIdx.x * blockDim.x + threadIdx.x) >> 6;
  int lane = threadIdx.x & 63;
  if (wid >= n) return;
  const int node = wid;
  const int base = off[node], cnt = deg[node];
  const int h2 = lane >> 3;
  const float adst2 = al_dst[node * H1 + h2];

  float m = -1e30f, l = 0.f, acc = 0.f;

#define ON1(aj, xj) { \
    float sc = lrelu((aj) + adst2); \
    float nm = fmaxf(m, sc); \
    float e1 = __expf(m - nm); \
    float p  = __expf(sc - nm); \
    acc = acc * e1 + p * (xj); \
    l   = l   * e1 + p; \
    m = nm; }

  int it = 0;
  for (; it + 4 <= cnt; it += 4) {
    int s0 = csr[base + it + 0], s1 = csr[base + it + 1];
    int s2 = csr[base + it + 2], s3 = csr[base + it + 3];
    float a0v = al_src[s0 * H1 + h2], a1v = al_src[s1 * H1 + h2];
    float a2v = al_src[s2 * H1 + h2], a3v = al_src[s3 * H1 + h2];
    float x0 = bf2f(xw1[(size_t)s0 * F1 + lane]);
    float x1 = bf2f(xw1[(size_t)s1 * F1 + lane]);
    float x2 = bf2f(xw1[(size_t)s2 * F1 + lane]);
    float x3 = bf2f(xw1[(size_t)s3 * F1 + lane]);
    ON1(a0v, x0); ON1(a1v, x1); ON1(a2v, x2); ON1(a3v, x3);
  }
  for (; it < cnt; ++it) {
    int s = csr[base + it];
    float av = al_src[s * H1 + h2];
    float xv = bf2f(xw1[(size_t)s * F1 + lane]);
    ON1(av, xv);
  }
  // self-loop
  {
    float av = al_src[node * H1 + h2];
    float xv = bf2f(xw1[(size_t)node * F1 + lane]);
    ON1(av, xv);
  }
#undef ON1

  float outv = acc / (l + 1e-16f) + b1[lane];
  h1[(size_t)node * F1 + lane] = outv > 0.f ? outv : __expf(outv) - 1.f;  // ELU
}

// ---------- GEMM2: xw2[n,40] = h1[n,64] @ W2[64,40], bf16 out ----------
__global__ __launch_bounds__(256) void gemm2_kernel(const float* __restrict__ h1,
    const float* __restrict__ W2, unsigned short* __restrict__ xw2, int n) {
  __shared__ float ws[F1 * C_OUT];
  int tid = threadIdx.x;
  for (int i = tid; i < F1 * C_OUT; i += 256) ws[i] = W2[i];
  __syncthreads();
  int node = blockIdx.x * 256 + tid;
  if (node >= n) return;
  const float4* row4 = (const float4*)(h1 + (size_t)node * F1);
  float acc[C_OUT];
#pragma unroll
  for (int j = 0; j < C_OUT; ++j) acc[j] = 0.f;
#pragma unroll 2
  for (int k4 = 0; k4 < 16; ++k4) {
    float4 xv = row4[k4];
    const float* w0 = &ws[(4 * k4 + 0) * C_OUT];
    const float* w1 = &ws[(4 * k4 + 1) * C_OUT];
    const float* w2 = &ws[(4 * k4 + 2) * C_OUT];
    const float* w3 = &ws[(4 * k4 + 3) * C_OUT];
#pragma unroll
    for (int j = 0; j < C_OUT; j += 4) {
      float4 v0 = *(const float4*)(w0 + j);
      float4 v1 = *(const float4*)(w1 + j);
      float4 v2 = *(const float4*)(w2 + j);
      float4 v3 = *(const float4*)(w3 + j);
      acc[j + 0] += xv.x * v0.x + xv.y * v1.x + xv.z * v2.x + xv.w * v3.x;
      acc[j + 1] += xv.x * v0.y + xv.y * v1.y + xv.z * v2.y + xv.w * v3.y;
      acc[j + 2] += xv.x * v0.z + xv.y * v1.z + xv.z * v2.z + xv.w * v3.z;
      acc[j + 3] += xv.x * v0.w + xv.y * v1.w + xv.z * v2.w + xv.w * v3.w;
    }
  }
  unsigned short* orow = xw2 + (size_t)node * C_OUT;
#pragma unroll
  for (int j = 0; j < C_OUT; j += 4) {
    ushort4 o;
    o.x = f2bf(acc[j + 0]); o.y = f2bf(acc[j + 1]);
    o.z = f2bf(acc[j + 2]); o.w = f2bf(acc[j + 3]);
    *(ushort4*)(orow + j) = o;
  }
}

// ---------- per-node attention logits, layer 2 ----------
__global__ __launch_bounds__(256) void al2_kernel(const unsigned short* __restrict__ xw2,
    const float* __restrict__ asrc, const float* __restrict__ adst,
    float* __restrict__ al_src, float* __restrict__ al_dst, int n) {
  __shared__ float sa[C_OUT], sd[C_OUT];
  if (threadIdx.x < C_OUT) {
    sa[threadIdx.x] = asrc[threadIdx.x];
    sd[threadIdx.x] = adst[threadIdx.x];
  }
  __syncthreads();
  int node = blockIdx.x * 256 + threadIdx.x;
  if (node >= n) return;
  const unsigned short* row = xw2 + (size_t)node * C_OUT;
  float s = 0.f, d = 0.f;
#pragma unroll
  for (int c = 0; c < C_OUT; ++c) {
    float v = bf2f(row[c]);
    s += v * sa[c];
    d += v * sd[c];
  }
  al_src[node] = s;
  al_dst[node] = d;
}

// ---------- layer-2 aggregation + log_softmax: wave per node, fused ----------
__global__ __launch_bounds__(256) void gat2_agg(const unsigned short* __restrict__ xw2,
    const float* __restrict__ al_src, const float* __restrict__ al_dst,
    const int* __restrict__ csr, const int* __restrict__ off, const int* __restrict__ deg,
    const float* __restrict__ b2, float* __restrict__ out, int n) {
  int wid = (blockIdx.x * blockDim.x + threadIdx.x) >> 6;
  int lane = threadIdx.x & 63;
  if (wid >= n) return;
  const int node = wid;
  const int base = off[node], cnt = deg[node];
  const float adst = al_dst[node];
  const bool act = lane < C_OUT;

  float m = -1e30f, l = 0.f, acc = 0.f;

#define ON2(aj, xj) { \
    float sc = lrelu((aj) + adst); \
    float nm = fmaxf(m, sc); \
    float e1 = __expf(m - nm); \
    float p  = __expf(sc - nm); \
    acc = acc * e1 + p * (xj); \
    l   = l   * e1 + p; \
    m = nm; }

  int it = 0;
  for (; it + 4 <= cnt; it += 4) {
    int s0 = csr[base + it + 0], s1 = csr[base + it + 1];
    int s2 = csr[base + it + 2], s3 = csr[base + it + 3];
    float a0v = al_src[s0], a1v = al_src[s1], a2v = al_src[s2], a3v = al_src[s3];
    float x0 = act ? bf2f(xw2[(size_t)s0 * C_OUT + lane]) : 0.f;
    float x1 = act ? bf2f(xw2[(size_t)s1 * C_OUT + lane]) : 0.f;
    float x2 = act ? bf2f(xw2[(size_t)s2 * C_OUT + lane]) : 0.f;
    float x3 = act ? bf2f(xw2[(size_t)s3 * C_OUT + lane]) : 0.f;
    ON2(a0v, x0); ON2(a1v, x1); ON2(a2v, x2); ON2(a3v, x3);
  }
  for (; it < cnt; ++it) {
    int s = csr[base + it];
    float av = al_src[s];
    float xv = act ? bf2f(xw2[(size_t)s * C_OUT + lane]) : 0.f;
    ON2(av, xv);
  }
  // self-loop
  {
    float av = al_src[node];
    float xv = act ? bf2f(xw2[(size_t)node * C_OUT + lane]) : 0.f;
    ON2(av, xv);
  }
#undef ON2

  float val = act ? acc / (l + 1e-16f) + b2[lane] : -1e30f;
  float mx = val;
#pragma unroll
  for (int mask = 1; mask <= 32; mask <<= 1) mx = fmaxf(mx, __shfl_xor(mx, mask));
  float ex = act ? __expf(val - mx) : 0.f;
  float sum = ex;
#pragma unroll
  for (int mask = 1; mask <= 32; mask <<= 1) sum += __shfl_xor(sum, mask);
  if (act) out[(size_t)node * C_OUT + lane] = val - mx - __logf(sum);
}

extern "C" void kernel_launch(void* const* d_in, const int* in_sizes, int n_in,
                              void* d_out, int out_size, void* d_ws, size_t ws_size,
                              hipStream_t stream) {
  const float* x   = (const float*)d_in[0];
  const int*   ei  = (const int*)d_in[1];
  const float* W1  = (const float*)d_in[2];
  const float* as1 = (const float*)d_in[3];
  const float* ad1 = (const float*)d_in[4];
  const float* b1  = (const float*)d_in[5];
  const float* W2  = (const float*)d_in[6];
  const float* as2 = (const float*)d_in[7];
  const float* ad2 = (const float*)d_in[8];
  const float* b2  = (const float*)d_in[9];
  float* out = (float*)d_out;

  const int n = in_sizes[0] / F_IN;
  const int e = in_sizes[1] / 2;
  const int* srcIdx = ei;
  const int* dstIdx = ei + e;
  const int nbuck = (n + BNODES - 1) >> BSHIFT;   // <= 256 for n <= 128k
  const int clen = nbuck * B1;                    // flat counter array length

  char* p = (char*)d_ws;
  auto take = [&](size_t bytes) {
    char* q = p;
    p += (bytes + 255) & ~(size_t)255;
    return q;
  };
  unsigned short* xw1 = (unsigned short*)take((size_t)n * F1 * 2);
  float* h1           = (float*)take((size_t)n * F1 * 4);
  unsigned short* xw2 = (unsigned short*)take((size_t)n * C_OUT * 2);
  float* alS1 = (float*)take((size_t)n * H1 * 4);
  float* alD1 = (float*)take((size_t)n * H1 * 4);
  float* alS2 = (float*)take((size_t)n * 4);
  float* alD2 = (float*)take((size_t)n * 4);
  int* deg  = (int*)take((size_t)n * 4);
  int* offb = (int*)take((size_t)n * 4);
  int* cnt  = (int*)take((size_t)clen * 4);
  int* cntS = (int*)take((size_t)clen * 4);
  int* bsum = (int*)take(4096);
  unsigned* binned = (unsigned*)take((size_t)e * 4);
  int* csr  = (int*)take((size_t)e * 4);

  dim3 b256(256);
  gemm1_kernel<<<dim3((n + 63) / 64), b256, 0, stream>>>(x, W1, xw1, n);
  al1_kernel<<<dim3((n * H1 + 255) / 256), b256, 0, stream>>>(xw1, as1, ad1, alS1, alD1, n);

  binhist_kernel<<<dim3(B1), b256, 0, stream>>>(dstIdx, cnt, e, nbuck);
  int nbScan = (clen + 255) / 256;
  scan1_kernel<<<dim3(nbScan), b256, 0, stream>>>(cnt, cntS, bsum, clen);
  scan2_kernel<<<dim3(1), dim3(1024), 0, stream>>>(bsum, nbScan);
  scan3_kernel<<<dim3(nbScan), b256, 0, stream>>>(cntS, bsum, clen);
  binscatter_kernel<<<dim3(B1), b256, 0, stream>>>(srcIdx, dstIdx, cntS, binned, e, nbuck);
  bucket_csr_kernel<<<dim3(nbuck), b256, 0, stream>>>(binned, cntS, deg, offb, csr, e, n, nbuck);

  gat1_agg<<<dim3((n + 3) / 4), b256, 0, stream>>>(xw1, alS1, alD1, csr, offb, deg, b1, h1, n);
  gemm2_kernel<<<dim3((n + 255) / 256), b256, 0, stream>>>(h1, W2, xw2, n);
  al2_kernel<<<dim3((n + 255) / 256), b256, 0, stream>>>(xw2, as2, ad2, alS2, alD2, n);
  gat2_agg<<<dim3((n + 3) / 4), b256, 0, stream>>>(xw2, alS2, alD2, csr, offb, deg, b2, out, n);
}

// Round 4
// 659.236 us; speedup vs baseline: 2.0318x; 1.1270x over previous
//
#include <hip/hip_runtime.h>
#include <cstdint>
#include <cstddef>

#define F_IN 1024
#define F1 64
#define H1 8
#define C1 8
#define C_OUT 40
#define NEG 0.2f
#define B1 256          // blocks in bin/scatter phase
#define BSHIFT 9        // bucket = dst >> 9 (512 nodes per bucket)
#define BNODES 512

typedef __attribute__((ext_vector_type(8))) short short8;
typedef __attribute__((ext_vector_type(4))) float f32x4;

static __device__ __forceinline__ float lrelu(float a) { return a > 0.f ? a : NEG * a; }

static __device__ __forceinline__ unsigned short f2bf(float f) {
  union { float f; unsigned u; } v; v.f = f;
  unsigned r = v.u + 0x7fff + ((v.u >> 16) & 1);  // RNE
  return (unsigned short)(r >> 16);
}
static __device__ __forceinline__ float bf2f(unsigned short h) {
  union { unsigned u; float f; } v; v.u = ((unsigned)h) << 16; return v.f;
}

// ---------- prep: W1T[64][1024] bf16 = transpose(W1[1024][64]) ----------
__global__ __launch_bounds__(256) void w1cvt_kernel(const float* __restrict__ W1,
                                                    unsigned short* __restrict__ w1t) {
  int i = blockIdx.x * 256 + threadIdx.x;           // 65536 total
  int c = i >> 10, k = i & 1023;
  w1t[i] = f2bf(W1[(size_t)k * F1 + c]);
}

// ---------- GEMM1 via MFMA, no LDS: xw1[n,64] = x[n,1024] @ W1, bf16 out ----------
__global__ __launch_bounds__(256) void gemm1_mfma(const float* __restrict__ x,
                                                  const unsigned short* __restrict__ w1t,
                                                  unsigned short* __restrict__ xw1, int n) {
  const int tid = threadIdx.x;
  const int wv = tid >> 6;          // wave 0..3 -> rows 16w..16w+15
  const int l = tid & 63;
  const int lr = l & 15;            // A row / B col / C col
  const int lg = l >> 4;            // k-group
  const int rowBase = blockIdx.x * 64 + wv * 16;
  int row = rowBase + lr;
  int rowc = row < n ? row : (n - 1);
  const float* px = x + (size_t)rowc * F_IN + lg * 8;

  f32x4 acc0 = {0.f, 0.f, 0.f, 0.f}, acc1 = acc0, acc2 = acc0, acc3 = acc0;

#pragma unroll 2
  for (int k0 = 0; k0 < F_IN; k0 += 32) {
    float4 xa = *(const float4*)(px + k0);
    float4 xb = *(const float4*)(px + k0 + 4);
    short8 af;
    af[0] = (short)f2bf(xa.x); af[1] = (short)f2bf(xa.y);
    af[2] = (short)f2bf(xa.z); af[3] = (short)f2bf(xa.w);
    af[4] = (short)f2bf(xb.x); af[5] = (short)f2bf(xb.y);
    af[6] = (short)f2bf(xb.z); af[7] = (short)f2bf(xb.w);
    const size_t kOff = (size_t)(k0 + lg * 8);
    short8 b0 = *(const short8*)(w1t + (size_t)(0 * 16 + lr) * F_IN + kOff);
    short8 b1 = *(const short8*)(w1t + (size_t)(1 * 16 + lr) * F_IN + kOff);
    short8 b2 = *(const short8*)(w1t + (size_t)(2 * 16 + lr) * F_IN + kOff);
    short8 b3 = *(const short8*)(w1t + (size_t)(3 * 16 + lr) * F_IN + kOff);
    acc0 = __builtin_amdgcn_mfma_f32_16x16x32_bf16(af, b0, acc0, 0, 0, 0);
    acc1 = __builtin_amdgcn_mfma_f32_16x16x32_bf16(af, b1, acc1, 0, 0, 0);
    acc2 = __builtin_amdgcn_mfma_f32_16x16x32_bf16(af, b2, acc2, 0, 0, 0);
    acc3 = __builtin_amdgcn_mfma_f32_16x16x32_bf16(af, b3, acc3, 0, 0, 0);
  }

  // C/D layout: col = lane&15, row = (lane>>4)*4 + reg   [m89-verified]
#pragma unroll
  for (int r = 0; r < 4; ++r) {
    int orow = rowBase + lg * 4 + r;
    if (orow < n) {
      unsigned short* po = xw1 + (size_t)orow * F1 + lr;
      po[0]  = f2bf(acc0[r]);
      po[16] = f2bf(acc1[r]);
      po[32] = f2bf(acc2[r]);
      po[48] = f2bf(acc3[r]);
    }
  }
}

// ---------- per-(node,head) attention logits, layer 1 ----------
__global__ __launch_bounds__(256) void al1_kernel(const unsigned short* __restrict__ xw1,
    const float* __restrict__ asrc, const float* __restrict__ adst,
    float* __restrict__ al_src, float* __restrict__ al_dst, int n) {
  int id = blockIdx.x * 256 + threadIdx.x;
  if (id >= n * H1) return;
  int node = id >> 3, h = id & 7;
  const unsigned short* row = xw1 + (size_t)node * F1 + h * C1;
  float s = 0.f, d = 0.f;
#pragma unroll
  for (int c = 0; c < C1; ++c) {
    float v = bf2f(row[c]);
    s += v * asrc[h * C1 + c];
    d += v * adst[h * C1 + c];
  }
  al_src[id] = s;
  al_dst[id] = d;
}

// ---------- CSR build via 2-level counting sort ----------
__global__ __launch_bounds__(256) void binhist_kernel(const int* __restrict__ dst,
    int* __restrict__ cnt, int e, int nbuck) {
  __shared__ int lh[256];
  int tid = threadIdx.x, blk = blockIdx.x;
  lh[tid] = 0;
  __syncthreads();
  int chunk = (e + gridDim.x - 1) / gridDim.x;
  int s = blk * chunk, en = min(e, s + chunk);
  for (int i = s + tid; i < en; i += 256) atomicAdd(&lh[dst[i] >> BSHIFT], 1);
  __syncthreads();
  if (tid < nbuck) cnt[tid * B1 + blk] = lh[tid];
}

__global__ __launch_bounds__(256) void scan1_kernel(const int* __restrict__ in,
    int* __restrict__ excl, int* __restrict__ bsum, int len) {
  __shared__ int s[256];
  int tid = threadIdx.x;
  int gid = blockIdx.x * 256 + tid;
  int v = gid < len ? in[gid] : 0;
  s[tid] = v;
  __syncthreads();
  for (int ofs = 1; ofs < 256; ofs <<= 1) {
    int t = (tid >= ofs) ? s[tid - ofs] : 0;
    __syncthreads();
    s[tid] += t;
    __syncthreads();
  }
  if (gid < len) excl[gid] = s[tid] - v;
  if (tid == 255) bsum[blockIdx.x] = s[255];
}

__global__ __launch_bounds__(1024) void scan2_kernel(int* __restrict__ bsum, int nb) {
  __shared__ int s[1024];
  int tid = threadIdx.x;
  int v = tid < nb ? bsum[tid] : 0;
  s[tid] = v;
  __syncthreads();
  for (int ofs = 1; ofs < 1024; ofs <<= 1) {
    int t = (tid >= ofs) ? s[tid - ofs] : 0;
    __syncthreads();
    s[tid] += t;
    __syncthreads();
  }
  if (tid < nb) bsum[tid] = s[tid] - v;  // exclusive
}

__global__ __launch_bounds__(256) void scan3_kernel(int* __restrict__ arr,
    const int* __restrict__ bsumx, int len) {
  int gid = blockIdx.x * 256 + threadIdx.x;
  if (gid < len) arr[gid] += bsumx[blockIdx.x];
}

__global__ __launch_bounds__(256) void binscatter_kernel(const int* __restrict__ src,
    const int* __restrict__ dst, const int* __restrict__ cntS,
    unsigned* __restrict__ binned, int e, int nbuck) {
  __shared__ int lcur[256];
  int tid = threadIdx.x, blk = blockIdx.x;
  if (tid < nbuck) lcur[tid] = cntS[tid * B1 + blk];
  __syncthreads();
  int chunk = (e + gridDim.x - 1) / gridDim.x;
  int s = blk * chunk, en = min(e, s + chunk);
  for (int i = s + tid; i < en; i += 256) {
    int d = dst[i];
    int pos = atomicAdd(&lcur[d >> BSHIFT], 1);
    binned[pos] = ((unsigned)(d & (BNODES - 1)) << 23) | (unsigned)src[i];
  }
}

__global__ __launch_bounds__(256) void bucket_csr_kernel(const unsigned* __restrict__ binned,
    const int* __restrict__ cntS, int* __restrict__ deg, int* __restrict__ off,
    int* __restrict__ csr, int e, int n, int nbuck) {
  int q = blockIdx.x, tid = threadIdx.x;
  int eBase = cntS[q * B1];
  int eEnd = (q + 1 < nbuck) ? cntS[(q + 1) * B1] : e;
  __shared__ int nh[BNODES], sc[BNODES], cu[BNODES];
  nh[tid] = 0; nh[tid + 256] = 0;
  __syncthreads();
  for (int i = eBase + tid; i < eEnd; i += 256) atomicAdd(&nh[binned[i] >> 23], 1);
  __syncthreads();
  sc[tid] = nh[tid]; sc[tid + 256] = nh[tid + 256];
  __syncthreads();
  for (int ofs = 1; ofs < BNODES; ofs <<= 1) {
    int a0 = sc[tid], a1 = sc[tid + 256];
    int b0 = (tid >= ofs) ? sc[tid - ofs] : 0;
    int b1 = (tid + 256 >= ofs) ? sc[tid + 256 - ofs] : 0;
    __syncthreads();
    sc[tid] = a0 + b0; sc[tid + 256] = a1 + b1;
    __syncthreads();
  }
  int e0 = sc[tid] - nh[tid], e1 = sc[tid + 256] - nh[tid + 256];
  cu[tid] = e0; cu[tid + 256] = e1;
  int node0 = q * BNODES + tid, node1 = node0 + 256;
  if (node0 < n) { deg[node0] = nh[tid];       off[node0] = eBase + e0; }
  if (node1 < n) { deg[node1] = nh[tid + 256]; off[node1] = eBase + e1; }
  __syncthreads();
  for (int i = eBase + tid; i < eEnd; i += 256) {
    unsigned v = binned[i];
    int pos = eBase + atomicAdd(&cu[v >> 23], 1);
    csr[pos] = (int)(v & 0x7FFFFF);
  }
}

// ---------- layer-1 aggregation: wave per node, fused online softmax ----------
__global__ __launch_bounds__(256) void gat1_agg(const unsigned short* __restrict__ xw1,
    const float* __restrict__ al_src, const float* __restrict__ al_dst,
    const int* __restrict__ csr, const int* __restrict__ off, const int* __restrict__ deg,
    const float* __restrict__ b1, float* __restrict__ h1, int n) {
  int wid = (blockIdx.x * blockDim.x + threadIdx.x) >> 6;
  int lane = threadIdx.x & 63;
  if (wid >= n) return;
  const int node = wid;
  const int base = off[node], cnt = deg[node];
  const int h2 = lane >> 3;
  const float adst2 = al_dst[node * H1 + h2];

  float m = -1e30f, l = 0.f, acc = 0.f;

#define ON1(aj, xj) { \
    float sc = lrelu((aj) + adst2); \
    float nm = fmaxf(m, sc); \
    float e1 = __expf(m - nm); \
    float p  = __expf(sc - nm); \
    acc = acc * e1 + p * (xj); \
    l   = l   * e1 + p; \
    m = nm; }

  int it = 0;
  for (; it + 4 <= cnt; it += 4) {
    int s0 = csr[base + it + 0], s1 = csr[base + it + 1];
    int s2 = csr[base + it + 2], s3 = csr[base + it + 3];
    float a0v = al_src[s0 * H1 + h2], a1v = al_src[s1 * H1 + h2];
    float a2v = al_src[s2 * H1 + h2], a3v = al_src[s3 * H1 + h2];
    float x0 = bf2f(xw1[(size_t)s0 * F1 + lane]);
    float x1 = bf2f(xw1[(size_t)s1 * F1 + lane]);
    float x2 = bf2f(xw1[(size_t)s2 * F1 + lane]);
    float x3 = bf2f(xw1[(size_t)s3 * F1 + lane]);
    ON1(a0v, x0); ON1(a1v, x1); ON1(a2v, x2); ON1(a3v, x3);
  }
  for (; it < cnt; ++it) {
    int s = csr[base + it];
    float av = al_src[s * H1 + h2];
    float xv = bf2f(xw1[(size_t)s * F1 + lane]);
    ON1(av, xv);
  }
  // self-loop
  {
    float av = al_src[node * H1 + h2];
    float xv = bf2f(xw1[(size_t)node * F1 + lane]);
    ON1(av, xv);
  }
#undef ON1

  float outv = acc / (l + 1e-16f) + b1[lane];
  h1[(size_t)node * F1 + lane] = outv > 0.f ? outv : __expf(outv) - 1.f;  // ELU
}

// ---------- GEMM2: xw2[n,40] = h1[n,64] @ W2[64,40], bf16 out ----------
__global__ __launch_bounds__(256) void gemm2_kernel(const float* __restrict__ h1,
    const float* __restrict__ W2, unsigned short* __restrict__ xw2, int n) {
  __shared__ float ws[F1 * C_OUT];
  int tid = threadIdx.x;
  for (int i = tid; i < F1 * C_OUT; i += 256) ws[i] = W2[i];
  __syncthreads();
  int node = blockIdx.x * 256 + tid;
  if (node >= n) return;
  const float4* row4 = (const float4*)(h1 + (size_t)node * F1);
  float acc[C_OUT];
#pragma unroll
  for (int j = 0; j < C_OUT; ++j) acc[j] = 0.f;
#pragma unroll 2
  for (int k4 = 0; k4 < 16; ++k4) {
    float4 xv = row4[k4];
    const float* w0 = &ws[(4 * k4 + 0) * C_OUT];
    const float* w1 = &ws[(4 * k4 + 1) * C_OUT];
    const float* w2 = &ws[(4 * k4 + 2) * C_OUT];
    const float* w3 = &ws[(4 * k4 + 3) * C_OUT];
#pragma unroll
    for (int j = 0; j < C_OUT; j += 4) {
      float4 v0 = *(const float4*)(w0 + j);
      float4 v1 = *(const float4*)(w1 + j);
      float4 v2 = *(const float4*)(w2 + j);
      float4 v3 = *(const float4*)(w3 + j);
      acc[j + 0] += xv.x * v0.x + xv.y * v1.x + xv.z * v2.x + xv.w * v3.x;
      acc[j + 1] += xv.x * v0.y + xv.y * v1.y + xv.z * v2.y + xv.w * v3.y;
      acc[j + 2] += xv.x * v0.z + xv.y * v1.z + xv.z * v2.z + xv.w * v3.z;
      acc[j + 3] += xv.x * v0.w + xv.y * v1.w + xv.z * v2.w + xv.w * v3.w;
    }
  }
  unsigned short* orow = xw2 + (size_t)node * C_OUT;
#pragma unroll
  for (int j = 0; j < C_OUT; j += 4) {
    ushort4 o;
    o.x = f2bf(acc[j + 0]); o.y = f2bf(acc[j + 1]);
    o.z = f2bf(acc[j + 2]); o.w = f2bf(acc[j + 3]);
    *(ushort4*)(orow + j) = o;
  }
}

// ---------- per-node attention logits, layer 2 ----------
__global__ __launch_bounds__(256) void al2_kernel(const unsigned short* __restrict__ xw2,
    const float* __restrict__ asrc, const float* __restrict__ adst,
    float* __restrict__ al_src, float* __restrict__ al_dst, int n) {
  __shared__ float sa[C_OUT], sd[C_OUT];
  if (threadIdx.x < C_OUT) {
    sa[threadIdx.x] = asrc[threadIdx.x];
    sd[threadIdx.x] = adst[threadIdx.x];
  }
  __syncthreads();
  int node = blockIdx.x * 256 + threadIdx.x;
  if (node >= n) return;
  const unsigned short* row = xw2 + (size_t)node * C_OUT;
  float s = 0.f, d = 0.f;
#pragma unroll
  for (int c = 0; c < C_OUT; ++c) {
    float v = bf2f(row[c]);
    s += v * sa[c];
    d += v * sd[c];
  }
  al_src[node] = s;
  al_dst[node] = d;
}

// ---------- layer-2 aggregation + log_softmax: wave per node, fused ----------
__global__ __launch_bounds__(256) void gat2_agg(const unsigned short* __restrict__ xw2,
    const float* __restrict__ al_src, const float* __restrict__ al_dst,
    const int* __restrict__ csr, const int* __restrict__ off, const int* __restrict__ deg,
    const float* __restrict__ b2, float* __restrict__ out, int n) {
  int wid = (blockIdx.x * blockDim.x + threadIdx.x) >> 6;
  int lane = threadIdx.x & 63;
  if (wid >= n) return;
  const int node = wid;
  const int base = off[node], cnt = deg[node];
  const float adst = al_dst[node];
  const bool act = lane < C_OUT;

  float m = -1e30f, l = 0.f, acc = 0.f;

#define ON2(aj, xj) { \
    float sc = lrelu((aj) + adst); \
    float nm = fmaxf(m, sc); \
    float e1 = __expf(m - nm); \
    float p  = __expf(sc - nm); \
    acc = acc * e1 + p * (xj); \
    l   = l   * e1 + p; \
    m = nm; }

  int it = 0;
  for (; it + 4 <= cnt; it += 4) {
    int s0 = csr[base + it + 0], s1 = csr[base + it + 1];
    int s2 = csr[base + it + 2], s3 = csr[base + it + 3];
    float a0v = al_src[s0], a1v = al_src[s1], a2v = al_src[s2], a3v = al_src[s3];
    float x0 = act ? bf2f(xw2[(size_t)s0 * C_OUT + lane]) : 0.f;
    float x1 = act ? bf2f(xw2[(size_t)s1 * C_OUT + lane]) : 0.f;
    float x2 = act ? bf2f(xw2[(size_t)s2 * C_OUT + lane]) : 0.f;
    float x3 = act ? bf2f(xw2[(size_t)s3 * C_OUT + lane]) : 0.f;
    ON2(a0v, x0); ON2(a1v, x1); ON2(a2v, x2); ON2(a3v, x3);
  }
  for (; it < cnt; ++it) {
    int s = csr[base + it];
    float av = al_src[s];
    float xv = act ? bf2f(xw2[(size_t)s * C_OUT + lane]) : 0.f;
    ON2(av, xv);
  }
  // self-loop
  {
    float av = al_src[node];
    float xv = act ? bf2f(xw2[(size_t)node * C_OUT + lane]) : 0.f;
    ON2(av, xv);
  }
#undef ON2

  float val = act ? acc / (l + 1e-16f) + b2[lane] : -1e30f;
  float mx = val;
#pragma unroll
  for (int mask = 1; mask <= 32; mask <<= 1) mx = fmaxf(mx, __shfl_xor(mx, mask));
  float ex = act ? __expf(val - mx) : 0.f;
  float sum = ex;
#pragma unroll
  for (int mask = 1; mask <= 32; mask <<= 1) sum += __shfl_xor(sum, mask);
  if (act) out[(size_t)node * C_OUT + lane] = val - mx - __logf(sum);
}

extern "C" void kernel_launch(void* const* d_in, const int* in_sizes, int n_in,
                              void* d_out, int out_size, void* d_ws, size_t ws_size,
                              hipStream_t stream) {
  const float* x   = (const float*)d_in[0];
  const int*   ei  = (const int*)d_in[1];
  const float* W1  = (const float*)d_in[2];
  const float* as1 = (const float*)d_in[3];
  const float* ad1 = (const float*)d_in[4];
  const float* b1  = (const float*)d_in[5];
  const float* W2  = (const float*)d_in[6];
  const float* as2 = (const float*)d_in[7];
  const float* ad2 = (const float*)d_in[8];
  const float* b2  = (const float*)d_in[9];
  float* out = (float*)d_out;

  const int n = in_sizes[0] / F_IN;
  const int e = in_sizes[1] / 2;
  const int* srcIdx = ei;
  const int* dstIdx = ei + e;
  const int nbuck = (n + BNODES - 1) >> BSHIFT;   // <= 256 for n <= 128k
  const int clen = nbuck * B1;                    // flat counter array length

  char* p = (char*)d_ws;
  auto take = [&](size_t bytes) {
    char* q = p;
    p += (bytes + 255) & ~(size_t)255;
    return q;
  };
  unsigned short* xw1 = (unsigned short*)take((size_t)n * F1 * 2);
  float* h1           = (float*)take((size_t)n * F1 * 4);
  unsigned short* xw2 = (unsigned short*)take((size_t)n * C_OUT * 2);
  unsigned short* w1t = (unsigned short*)take((size_t)F_IN * F1 * 2);
  float* alS1 = (float*)take((size_t)n * H1 * 4);
  float* alD1 = (float*)take((size_t)n * H1 * 4);
  float* alS2 = (float*)take((size_t)n * 4);
  float* alD2 = (float*)take((size_t)n * 4);
  int* deg  = (int*)take((size_t)n * 4);
  int* offb = (int*)take((size_t)n * 4);
  int* cnt  = (int*)take((size_t)clen * 4);
  int* cntS = (int*)take((size_t)clen * 4);
  int* bsum = (int*)take(4096);
  unsigned* binned = (unsigned*)take((size_t)e * 4);
  int* csr  = (int*)take((size_t)e * 4);

  dim3 b256(256);
  w1cvt_kernel<<<dim3((F_IN * F1) / 256), b256, 0, stream>>>(W1, w1t);
  gemm1_mfma<<<dim3((n + 63) / 64), b256, 0, stream>>>(x, w1t, xw1, n);
  al1_kernel<<<dim3((n * H1 + 255) / 256), b256, 0, stream>>>(xw1, as1, ad1, alS1, alD1, n);

  binhist_kernel<<<dim3(B1), b256, 0, stream>>>(dstIdx, cnt, e, nbuck);
  int nbScan = (clen + 255) / 256;
  scan1_kernel<<<dim3(nbScan), b256, 0, stream>>>(cnt, cntS, bsum, clen);
  scan2_kernel<<<dim3(1), dim3(1024), 0, stream>>>(bsum, nbScan);
  scan3_kernel<<<dim3(nbScan), b256, 0, stream>>>(cntS, bsum, clen);
  binscatter_kernel<<<dim3(B1), b256, 0, stream>>>(srcIdx, dstIdx, cntS, binned, e, nbuck);
  bucket_csr_kernel<<<dim3(nbuck), b256, 0, stream>>>(binned, cntS, deg, offb, csr, e, n, nbuck);

  gat1_agg<<<dim3((n + 3) / 4), b256, 0, stream>>>(xw1, alS1, alD1, csr, offb, deg, b1, h1, n);
  gemm2_kernel<<<dim3((n + 255) / 256), b256, 0, stream>>>(h1, W2, xw2, n);
  al2_kernel<<<dim3((n + 255) / 256), b256, 0, stream>>>(xw2, as2, ad2, alS2, alD2, n);
  gat2_agg<<<dim3((n + 3) / 4), b256, 0, stream>>>(xw2, alS2, alD2, csr, offb, deg, b2, out, n);
}

// Round 5
// 627.871 us; speedup vs baseline: 2.1333x; 1.0500x over previous
//
#include <hip/hip_runtime.h>
#include <hip/hip_bf16.h>
#include <cstdint>
#include <cstddef>

#define F_IN 1024
#define F1 64
#define H1 8
#define C1 8
#define C_OUT 40
#define NEG 0.2f
#define B1 256          // blocks in bin/scatter phase
#define BSHIFT 9        // bucket = dst >> 9 (512 nodes per bucket)
#define BNODES 512

typedef __attribute__((ext_vector_type(8))) short short8;
typedef __attribute__((ext_vector_type(4))) float f32x4;

static __device__ __forceinline__ float lrelu(float a) { return a > 0.f ? a : NEG * a; }

static __device__ __forceinline__ unsigned short f2bf(float f) {
  union { float f; unsigned u; } v; v.f = f;
  unsigned r = v.u + 0x7fff + ((v.u >> 16) & 1);  // RNE
  return (unsigned short)(r >> 16);
}
static __device__ __forceinline__ float bf2f(unsigned short h) {
  union { unsigned u; float f; } v; v.u = ((unsigned)h) << 16; return v.f;
}
// packed f32x2 -> bf16x2 (compiler emits v_cvt_pk_bf16_f32)
static __device__ __forceinline__ unsigned pkbf(float a, float b) {
  union { __hip_bfloat162 h; unsigned u; } c;
  c.h = __float22bfloat162_rn(float2{a, b});
  return c.u;
}

// ---------- prep: W1T[64][1024] bf16 = transpose(W1[1024][64]) ----------
__global__ __launch_bounds__(256) void w1cvt_kernel(const float* __restrict__ W1,
                                                    unsigned short* __restrict__ w1t) {
  int i = blockIdx.x * 256 + threadIdx.x;           // 65536 total
  int c = i >> 10, k = i & 1023;
  w1t[i] = f2bf(W1[(size_t)k * F1 + c]);
}

// ---------- GEMM1 via MFMA, no LDS: xw1[n,64] = x[n,1024] @ W1, bf16 out ----------
__global__ __launch_bounds__(256) void gemm1_mfma(const float* __restrict__ x,
                                                  const unsigned short* __restrict__ w1t,
                                                  unsigned short* __restrict__ xw1, int n) {
  const int tid = threadIdx.x;
  const int wv = tid >> 6;          // wave 0..3 -> rows 16w..16w+15
  const int l = tid & 63;
  const int lr = l & 15;            // A row / B col / C col
  const int lg = l >> 4;            // k-group
  const int rowBase = blockIdx.x * 64 + wv * 16;
  int row = rowBase + lr;
  int rowc = row < n ? row : (n - 1);
  const float* px = x + (size_t)rowc * F_IN + lg * 8;

  f32x4 acc0 = {0.f, 0.f, 0.f, 0.f}, acc1 = acc0, acc2 = acc0, acc3 = acc0;

#pragma unroll 4
  for (int k0 = 0; k0 < F_IN; k0 += 32) {
    float4 xa = *(const float4*)(px + k0);
    float4 xb = *(const float4*)(px + k0 + 4);
    union { short8 s; unsigned u[4]; } af;
    af.u[0] = pkbf(xa.x, xa.y);
    af.u[1] = pkbf(xa.z, xa.w);
    af.u[2] = pkbf(xb.x, xb.y);
    af.u[3] = pkbf(xb.z, xb.w);
    const size_t kOff = (size_t)(k0 + lg * 8);
    short8 b0 = *(const short8*)(w1t + (size_t)(0 * 16 + lr) * F_IN + kOff);
    short8 b1 = *(const short8*)(w1t + (size_t)(1 * 16 + lr) * F_IN + kOff);
    short8 b2 = *(const short8*)(w1t + (size_t)(2 * 16 + lr) * F_IN + kOff);
    short8 b3 = *(const short8*)(w1t + (size_t)(3 * 16 + lr) * F_IN + kOff);
    acc0 = __builtin_amdgcn_mfma_f32_16x16x32_bf16(af.s, b0, acc0, 0, 0, 0);
    acc1 = __builtin_amdgcn_mfma_f32_16x16x32_bf16(af.s, b1, acc1, 0, 0, 0);
    acc2 = __builtin_amdgcn_mfma_f32_16x16x32_bf16(af.s, b2, acc2, 0, 0, 0);
    acc3 = __builtin_amdgcn_mfma_f32_16x16x32_bf16(af.s, b3, acc3, 0, 0, 0);
  }

  // C/D layout: col = lane&15, row = (lane>>4)*4 + reg   [m89-verified]
#pragma unroll
  for (int r = 0; r < 4; ++r) {
    int orow = rowBase + lg * 4 + r;
    if (orow < n) {
      unsigned short* po = xw1 + (size_t)orow * F1 + lr;
      po[0]  = f2bf(acc0[r]);
      po[16] = f2bf(acc1[r]);
      po[32] = f2bf(acc2[r]);
      po[48] = f2bf(acc3[r]);
    }
  }
}

// ---------- per-(node,head) attention logits, layer 1 ----------
__global__ __launch_bounds__(256) void al1_kernel(const unsigned short* __restrict__ xw1,
    const float* __restrict__ asrc, const float* __restrict__ adst,
    float* __restrict__ al_src, float* __restrict__ al_dst, int n) {
  int id = blockIdx.x * 256 + threadIdx.x;
  if (id >= n * H1) return;
  int node = id >> 3, h = id & 7;
  const unsigned short* row = xw1 + (size_t)node * F1 + h * C1;
  float s = 0.f, d = 0.f;
#pragma unroll
  for (int c = 0; c < C1; ++c) {
    float v = bf2f(row[c]);
    s += v * asrc[h * C1 + c];
    d += v * adst[h * C1 + c];
  }
  al_src[id] = s;
  al_dst[id] = d;
}

// ---------- CSR build via 2-level counting sort ----------
__global__ __launch_bounds__(256) void binhist_kernel(const int* __restrict__ dst,
    int* __restrict__ cnt, int e, int nbuck) {
  __shared__ int lh[256];
  int tid = threadIdx.x, blk = blockIdx.x;
  lh[tid] = 0;
  __syncthreads();
  int chunk = (e + gridDim.x - 1) / gridDim.x;
  int s = blk * chunk, en = min(e, s + chunk);
  for (int i = s + tid; i < en; i += 256) atomicAdd(&lh[dst[i] >> BSHIFT], 1);
  __syncthreads();
  if (tid < nbuck) cnt[tid * B1 + blk] = lh[tid];
}

__global__ __launch_bounds__(256) void scan1_kernel(const int* __restrict__ in,
    int* __restrict__ excl, int* __restrict__ bsum, int len) {
  __shared__ int s[256];
  int tid = threadIdx.x;
  int gid = blockIdx.x * 256 + tid;
  int v = gid < len ? in[gid] : 0;
  s[tid] = v;
  __syncthreads();
  for (int ofs = 1; ofs < 256; ofs <<= 1) {
    int t = (tid >= ofs) ? s[tid - ofs] : 0;
    __syncthreads();
    s[tid] += t;
    __syncthreads();
  }
  if (gid < len) excl[gid] = s[tid] - v;
  if (tid == 255) bsum[blockIdx.x] = s[255];
}

__global__ __launch_bounds__(1024) void scan2_kernel(int* __restrict__ bsum, int nb) {
  __shared__ int s[1024];
  int tid = threadIdx.x;
  int v = tid < nb ? bsum[tid] : 0;
  s[tid] = v;
  __syncthreads();
  for (int ofs = 1; ofs < 1024; ofs <<= 1) {
    int t = (tid >= ofs) ? s[tid - ofs] : 0;
    __syncthreads();
    s[tid] += t;
    __syncthreads();
  }
  if (tid < nb) bsum[tid] = s[tid] - v;  // exclusive
}

__global__ __launch_bounds__(256) void scan3_kernel(int* __restrict__ arr,
    const int* __restrict__ bsumx, int len) {
  int gid = blockIdx.x * 256 + threadIdx.x;
  if (gid < len) arr[gid] += bsumx[blockIdx.x];
}

__global__ __launch_bounds__(256) void binscatter_kernel(const int* __restrict__ src,
    const int* __restrict__ dst, const int* __restrict__ cntS,
    unsigned* __restrict__ binned, int e, int nbuck) {
  __shared__ int lcur[256];
  int tid = threadIdx.x, blk = blockIdx.x;
  if (tid < nbuck) lcur[tid] = cntS[tid * B1 + blk];
  __syncthreads();
  int chunk = (e + gridDim.x - 1) / gridDim.x;
  int s = blk * chunk, en = min(e, s + chunk);
  for (int i = s + tid; i < en; i += 256) {
    int d = dst[i];
    int pos = atomicAdd(&lcur[d >> BSHIFT], 1);
    binned[pos] = ((unsigned)(d & (BNODES - 1)) << 23) | (unsigned)src[i];
  }
}

__global__ __launch_bounds__(256) void bucket_csr_kernel(const unsigned* __restrict__ binned,
    const int* __restrict__ cntS, int* __restrict__ deg, int* __restrict__ off,
    int* __restrict__ csr, int e, int n, int nbuck) {
  int q = blockIdx.x, tid = threadIdx.x;
  int eBase = cntS[q * B1];
  int eEnd = (q + 1 < nbuck) ? cntS[(q + 1) * B1] : e;
  __shared__ int nh[BNODES], sc[BNODES], cu[BNODES];
  nh[tid] = 0; nh[tid + 256] = 0;
  __syncthreads();
  for (int i = eBase + tid; i < eEnd; i += 256) atomicAdd(&nh[binned[i] >> 23], 1);
  __syncthreads();
  sc[tid] = nh[tid]; sc[tid + 256] = nh[tid + 256];
  __syncthreads();
  for (int ofs = 1; ofs < BNODES; ofs <<= 1) {
    int a0 = sc[tid], a1 = sc[tid + 256];
    int b0 = (tid >= ofs) ? sc[tid - ofs] : 0;
    int b1 = (tid + 256 >= ofs) ? sc[tid + 256 - ofs] : 0;
    __syncthreads();
    sc[tid] = a0 + b0; sc[tid + 256] = a1 + b1;
    __syncthreads();
  }
  int e0 = sc[tid] - nh[tid], e1 = sc[tid + 256] - nh[tid + 256];
  cu[tid] = e0; cu[tid + 256] = e1;
  int node0 = q * BNODES + tid, node1 = node0 + 256;
  if (node0 < n) { deg[node0] = nh[tid];       off[node0] = eBase + e0; }
  if (node1 < n) { deg[node1] = nh[tid + 256]; off[node1] = eBase + e1; }
  __syncthreads();
  for (int i = eBase + tid; i < eEnd; i += 256) {
    unsigned v = binned[i];
    int pos = eBase + atomicAdd(&cu[v >> 23], 1);
    csr[pos] = (int)(v & 0x7FFFFF);
  }
}

// ---------- layer-1 aggregation: wave per node, direct-exp softmax ----------
// scores = lrelu(al) are bounded (|sc| < ~10 for N(0,1) logits), so
// exp without max-subtraction is safe in fp32 and alpha = p/sum(p) is
// mathematically identical to the max-shifted form.
__global__ __launch_bounds__(256) void gat1_agg(const unsigned short* __restrict__ xw1,
    const float* __restrict__ al_src, const float* __restrict__ al_dst,
    const int* __restrict__ csr, const int* __restrict__ off, const int* __restrict__ deg,
    const float* __restrict__ b1, float* __restrict__ h1, int n) {
  int wid = (blockIdx.x * blockDim.x + threadIdx.x) >> 6;
  int lane = threadIdx.x & 63;
  if (wid >= n) return;
  const int node = wid;
  const int base = off[node], cnt = deg[node];
  const int h2 = lane >> 3;
  const float adst2 = al_dst[node * H1 + h2];

  float l = 0.f, acc = 0.f;

#define ON1(aj, xj) { \
    float sc = lrelu((aj) + adst2); \
    float p = __expf(sc); \
    acc += p * (xj); \
    l   += p; }

  int it = 0;
  for (; it + 8 <= cnt; it += 8) {
    int sL[8];
#pragma unroll
    for (int j = 0; j < 8; ++j) sL[j] = csr[base + it + j];
    float aL[8], xL[8];
#pragma unroll
    for (int j = 0; j < 8; ++j) aL[j] = al_src[sL[j] * H1 + h2];
#pragma unroll
    for (int j = 0; j < 8; ++j) xL[j] = bf2f(xw1[(size_t)sL[j] * F1 + lane]);
#pragma unroll
    for (int j = 0; j < 8; ++j) { ON1(aL[j], xL[j]); }
  }
  for (; it < cnt; ++it) {
    int s = csr[base + it];
    float av = al_src[s * H1 + h2];
    float xv = bf2f(xw1[(size_t)s * F1 + lane]);
    ON1(av, xv);
  }
  // self-loop
  {
    float av = al_src[node * H1 + h2];
    float xv = bf2f(xw1[(size_t)node * F1 + lane]);
    ON1(av, xv);
  }
#undef ON1

  float outv = acc / (l + 1e-16f) + b1[lane];
  h1[(size_t)node * F1 + lane] = outv > 0.f ? outv : __expf(outv) - 1.f;  // ELU
}

// ---------- GEMM2: xw2[n,40] = h1[n,64] @ W2[64,40], bf16 out ----------
__global__ __launch_bounds__(256) void gemm2_kernel(const float* __restrict__ h1,
    const float* __restrict__ W2, unsigned short* __restrict__ xw2, int n) {
  __shared__ float ws[F1 * C_OUT];
  int tid = threadIdx.x;
  for (int i = tid; i < F1 * C_OUT; i += 256) ws[i] = W2[i];
  __syncthreads();
  int node = blockIdx.x * 256 + tid;
  if (node >= n) return;
  const float4* row4 = (const float4*)(h1 + (size_t)node * F1);
  float acc[C_OUT];
#pragma unroll
  for (int j = 0; j < C_OUT; ++j) acc[j] = 0.f;
#pragma unroll 2
  for (int k4 = 0; k4 < 16; ++k4) {
    float4 xv = row4[k4];
    const float* w0 = &ws[(4 * k4 + 0) * C_OUT];
    const float* w1 = &ws[(4 * k4 + 1) * C_OUT];
    const float* w2 = &ws[(4 * k4 + 2) * C_OUT];
    const float* w3 = &ws[(4 * k4 + 3) * C_OUT];
#pragma unroll
    for (int j = 0; j < C_OUT; j += 4) {
      float4 v0 = *(const float4*)(w0 + j);
      float4 v1 = *(const float4*)(w1 + j);
      float4 v2 = *(const float4*)(w2 + j);
      float4 v3 = *(const float4*)(w3 + j);
      acc[j + 0] += xv.x * v0.x + xv.y * v1.x + xv.z * v2.x + xv.w * v3.x;
      acc[j + 1] += xv.x * v0.y + xv.y * v1.y + xv.z * v2.y + xv.w * v3.y;
      acc[j + 2] += xv.x * v0.z + xv.y * v1.z + xv.z * v2.z + xv.w * v3.z;
      acc[j + 3] += xv.x * v0.w + xv.y * v1.w + xv.z * v2.w + xv.w * v3.w;
    }
  }
  unsigned short* orow = xw2 + (size_t)node * C_OUT;
#pragma unroll
  for (int j = 0; j < C_OUT; j += 4) {
    ushort4 o;
    o.x = f2bf(acc[j + 0]); o.y = f2bf(acc[j + 1]);
    o.z = f2bf(acc[j + 2]); o.w = f2bf(acc[j + 3]);
    *(ushort4*)(orow + j) = o;
  }
}

// ---------- per-node attention logits, layer 2 ----------
__global__ __launch_bounds__(256) void al2_kernel(const unsigned short* __restrict__ xw2,
    const float* __restrict__ asrc, const float* __restrict__ adst,
    float* __restrict__ al_src, float* __restrict__ al_dst, int n) {
  __shared__ float sa[C_OUT], sd[C_OUT];
  if (threadIdx.x < C_OUT) {
    sa[threadIdx.x] = asrc[threadIdx.x];
    sd[threadIdx.x] = adst[threadIdx.x];
  }
  __syncthreads();
  int node = blockIdx.x * 256 + threadIdx.x;
  if (node >= n) return;
  const unsigned short* row = xw2 + (size_t)node * C_OUT;
  float s = 0.f, d = 0.f;
#pragma unroll
  for (int c = 0; c < C_OUT; ++c) {
    float v = bf2f(row[c]);
    s += v * sa[c];
    d += v * sd[c];
  }
  al_src[node] = s;
  al_dst[node] = d;
}

// ---------- layer-2 aggregation + log_softmax: wave per node ----------
__global__ __launch_bounds__(256) void gat2_agg(const unsigned short* __restrict__ xw2,
    const float* __restrict__ al_src, const float* __restrict__ al_dst,
    const int* __restrict__ csr, const int* __restrict__ off, const int* __restrict__ deg,
    const float* __restrict__ b2, float* __restrict__ out, int n) {
  int wid = (blockIdx.x * blockDim.x + threadIdx.x) >> 6;
  int lane = threadIdx.x & 63;
  if (wid >= n) return;
  const int node = wid;
  const int base = off[node], cnt = deg[node];
  const float adst = al_dst[node];
  const bool act = lane < C_OUT;

  float l = 0.f, acc = 0.f;

#define ON2(aj, xj) { \
    float sc = lrelu((aj) + adst); \
    float p = __expf(sc); \
    acc += p * (xj); \
    l   += p; }

  int it = 0;
  for (; it + 8 <= cnt; it += 8) {
    int sL[8];
#pragma unroll
    for (int j = 0; j < 8; ++j) sL[j] = csr[base + it + j];
    float aL[8], xL[8];
#pragma unroll
    for (int j = 0; j < 8; ++j) aL[j] = al_src[sL[j]];
#pragma unroll
    for (int j = 0; j < 8; ++j) xL[j] = act ? bf2f(xw2[(size_t)sL[j] * C_OUT + lane]) : 0.f;
#pragma unroll
    for (int j = 0; j < 8; ++j) { ON2(aL[j], xL[j]); }
  }
  for (; it < cnt; ++it) {
    int s = csr[base + it];
    float av = al_src[s];
    float xv = act ? bf2f(xw2[(size_t)s * C_OUT + lane]) : 0.f;
    ON2(av, xv);
  }
  // self-loop
  {
    float av = al_src[node];
    float xv = act ? bf2f(xw2[(size_t)node * C_OUT + lane]) : 0.f;
    ON2(av, xv);
  }
#undef ON2

  float val = act ? acc / (l + 1e-16f) + b2[lane] : -1e30f;
  float mx = val;
#pragma unroll
  for (int mask = 1; mask <= 32; mask <<= 1) mx = fmaxf(mx, __shfl_xor(mx, mask));
  float ex = act ? __expf(val - mx) : 0.f;
  float sum = ex;
#pragma unroll
  for (int mask = 1; mask <= 32; mask <<= 1) sum += __shfl_xor(sum, mask);
  if (act) out[(size_t)node * C_OUT + lane] = val - mx - __logf(sum);
}

extern "C" void kernel_launch(void* const* d_in, const int* in_sizes, int n_in,
                              void* d_out, int out_size, void* d_ws, size_t ws_size,
                              hipStream_t stream) {
  const float* x   = (const float*)d_in[0];
  const int*   ei  = (const int*)d_in[1];
  const float* W1  = (const float*)d_in[2];
  const float* as1 = (const float*)d_in[3];
  const float* ad1 = (const float*)d_in[4];
  const float* b1  = (const float*)d_in[5];
  const float* W2  = (const float*)d_in[6];
  const float* as2 = (const float*)d_in[7];
  const float* ad2 = (const float*)d_in[8];
  const float* b2  = (const float*)d_in[9];
  float* out = (float*)d_out;

  const int n = in_sizes[0] / F_IN;
  const int e = in_sizes[1] / 2;
  const int* srcIdx = ei;
  const int* dstIdx = ei + e;
  const int nbuck = (n + BNODES - 1) >> BSHIFT;   // <= 256 for n <= 128k
  const int clen = nbuck * B1;                    // flat counter array length

  char* p = (char*)d_ws;
  auto take = [&](size_t bytes) {
    char* q = p;
    p += (bytes + 255) & ~(size_t)255;
    return q;
  };
  unsigned short* xw1 = (unsigned short*)take((size_t)n * F1 * 2);
  float* h1           = (float*)take((size_t)n * F1 * 4);
  unsigned short* xw2 = (unsigned short*)take((size_t)n * C_OUT * 2);
  unsigned short* w1t = (unsigned short*)take((size_t)F_IN * F1 * 2);
  float* alS1 = (float*)take((size_t)n * H1 * 4);
  float* alD1 = (float*)take((size_t)n * H1 * 4);
  float* alS2 = (float*)take((size_t)n * 4);
  float* alD2 = (float*)take((size_t)n * 4);
  int* deg  = (int*)take((size_t)n * 4);
  int* offb = (int*)take((size_t)n * 4);
  int* cnt  = (int*)take((size_t)clen * 4);
  int* cntS = (int*)take((size_t)clen * 4);
  int* bsum = (int*)take(4096);
  unsigned* binned = (unsigned*)take((size_t)e * 4);
  int* csr  = (int*)take((size_t)e * 4);

  dim3 b256(256);
  w1cvt_kernel<<<dim3((F_IN * F1) / 256), b256, 0, stream>>>(W1, w1t);
  gemm1_mfma<<<dim3((n + 63) / 64), b256, 0, stream>>>(x, w1t, xw1, n);
  al1_kernel<<<dim3((n * H1 + 255) / 256), b256, 0, stream>>>(xw1, as1, ad1, alS1, alD1, n);

  binhist_kernel<<<dim3(B1), b256, 0, stream>>>(dstIdx, cnt, e, nbuck);
  int nbScan = (clen + 255) / 256;
  scan1_kernel<<<dim3(nbScan), b256, 0, stream>>>(cnt, cntS, bsum, clen);
  scan2_kernel<<<dim3(1), dim3(1024), 0, stream>>>(bsum, nbScan);
  scan3_kernel<<<dim3(nbScan), b256, 0, stream>>>(cntS, bsum, clen);
  binscatter_kernel<<<dim3(B1), b256, 0, stream>>>(srcIdx, dstIdx, cntS, binned, e, nbuck);
  bucket_csr_kernel<<<dim3(nbuck), b256, 0, stream>>>(binned, cntS, deg, offb, csr, e, n, nbuck);

  gat1_agg<<<dim3((n + 3) / 4), b256, 0, stream>>>(xw1, alS1, alD1, csr, offb, deg, b1, h1, n);
  gemm2_kernel<<<dim3((n + 255) / 256), b256, 0, stream>>>(h1, W2, xw2, n);
  al2_kernel<<<dim3((n + 255) / 256), b256, 0, stream>>>(xw2, as2, ad2, alS2, alD2, n);
  gat2_agg<<<dim3((n + 3) / 4), b256, 0, stream>>>(xw2, alS2, alD2, csr, offb, deg, b2, out, n);
}

// Round 6
// 591.996 us; speedup vs baseline: 2.2626x; 1.0606x over previous
//
#include <hip/hip_runtime.h>
#include <hip/hip_bf16.h>
#include <cstdint>
#include <cstddef>

#define F_IN 1024
#define F1 64
#define H1 8
#define C1 8
#define C_OUT 40
#define NEG 0.2f
#define B1 256          // blocks in bin/scatter phase
#define BSHIFT 9        // bucket = dst >> 9 (512 nodes per bucket)
#define BNODES 512

typedef __attribute__((ext_vector_type(8))) short short8;
typedef __attribute__((ext_vector_type(4))) float f32x4;

static __device__ __forceinline__ float lrelu(float a) { return a > 0.f ? a : NEG * a; }

static __device__ __forceinline__ unsigned short f2bf(float f) {
  union { float f; unsigned u; } v; v.f = f;
  unsigned r = v.u + 0x7fff + ((v.u >> 16) & 1);  // RNE
  return (unsigned short)(r >> 16);
}
static __device__ __forceinline__ float bf2f(unsigned short h) {
  union { unsigned u; float f; } v; v.u = ((unsigned)h) << 16; return v.f;
}
// packed f32x2 -> bf16x2 (compiler emits v_cvt_pk_bf16_f32)
static __device__ __forceinline__ unsigned pkbf(float a, float b) {
  union { __hip_bfloat162 h; unsigned u; } c;
  c.h = __float22bfloat162_rn(float2{a, b});
  return c.u;
}
static __device__ __forceinline__ int rfl(int v) {
  return __builtin_amdgcn_readfirstlane(v);
}

// ---------- prep: W1T[64][1024] bf16 = transpose(W1[1024][64]) ----------
__global__ __launch_bounds__(256) void w1cvt_kernel(const float* __restrict__ W1,
                                                    unsigned short* __restrict__ w1t) {
  int i = blockIdx.x * 256 + threadIdx.x;           // 65536 total
  int c = i >> 10, k = i & 1023;
  w1t[i] = f2bf(W1[(size_t)k * F1 + c]);
}

// ---------- GEMM1 via MFMA, no LDS: xw1[n,64] = x[n,1024] @ W1, bf16 out ----------
__global__ __launch_bounds__(256) void gemm1_mfma(const float* __restrict__ x,
                                                  const unsigned short* __restrict__ w1t,
                                                  unsigned short* __restrict__ xw1, int n) {
  const int tid = threadIdx.x;
  const int wv = tid >> 6;          // wave 0..3 -> rows 16w..16w+15
  const int l = tid & 63;
  const int lr = l & 15;            // A row / B col / C col
  const int lg = l >> 4;            // k-group
  const int rowBase = blockIdx.x * 64 + wv * 16;
  int row = rowBase + lr;
  int rowc = row < n ? row : (n - 1);
  const float* px = x + (size_t)rowc * F_IN + lg * 8;

  f32x4 acc0 = {0.f, 0.f, 0.f, 0.f}, acc1 = acc0, acc2 = acc0, acc3 = acc0;

#pragma unroll 4
  for (int k0 = 0; k0 < F_IN; k0 += 32) {
    float4 xa = *(const float4*)(px + k0);
    float4 xb = *(const float4*)(px + k0 + 4);
    union { short8 s; unsigned u[4]; } af;
    af.u[0] = pkbf(xa.x, xa.y);
    af.u[1] = pkbf(xa.z, xa.w);
    af.u[2] = pkbf(xb.x, xb.y);
    af.u[3] = pkbf(xb.z, xb.w);
    const size_t kOff = (size_t)(k0 + lg * 8);
    short8 b0 = *(const short8*)(w1t + (size_t)(0 * 16 + lr) * F_IN + kOff);
    short8 b1 = *(const short8*)(w1t + (size_t)(1 * 16 + lr) * F_IN + kOff);
    short8 b2 = *(const short8*)(w1t + (size_t)(2 * 16 + lr) * F_IN + kOff);
    short8 b3 = *(const short8*)(w1t + (size_t)(3 * 16 + lr) * F_IN + kOff);
    acc0 = __builtin_amdgcn_mfma_f32_16x16x32_bf16(af.s, b0, acc0, 0, 0, 0);
    acc1 = __builtin_amdgcn_mfma_f32_16x16x32_bf16(af.s, b1, acc1, 0, 0, 0);
    acc2 = __builtin_amdgcn_mfma_f32_16x16x32_bf16(af.s, b2, acc2, 0, 0, 0);
    acc3 = __builtin_amdgcn_mfma_f32_16x16x32_bf16(af.s, b3, acc3, 0, 0, 0);
  }

  // C/D layout: col = lane&15, row = (lane>>4)*4 + reg   [m89-verified]
#pragma unroll
  for (int r = 0; r < 4; ++r) {
    int orow = rowBase + lg * 4 + r;
    if (orow < n) {
      unsigned short* po = xw1 + (size_t)orow * F1 + lr;
      po[0]  = f2bf(acc0[r]);
      po[16] = f2bf(acc1[r]);
      po[32] = f2bf(acc2[r]);
      po[48] = f2bf(acc3[r]);
    }
  }
}

// ---------- per-(node,head) attention logits, layer 1 ----------
__global__ __launch_bounds__(256) void al1_kernel(const unsigned short* __restrict__ xw1,
    const float* __restrict__ asrc, const float* __restrict__ adst,
    float* __restrict__ al_src, float* __restrict__ al_dst, int n) {
  int id = blockIdx.x * 256 + threadIdx.x;
  if (id >= n * H1) return;
  int node = id >> 3, h = id & 7;
  const unsigned short* row = xw1 + (size_t)node * F1 + h * C1;
  float s = 0.f, d = 0.f;
#pragma unroll
  for (int c = 0; c < C1; ++c) {
    float v = bf2f(row[c]);
    s += v * asrc[h * C1 + c];
    d += v * adst[h * C1 + c];
  }
  al_src[id] = s;
  al_dst[id] = d;
}

// ---------- CSR build via 2-level counting sort ----------
__global__ __launch_bounds__(256) void binhist_kernel(const int* __restrict__ dst,
    int* __restrict__ cnt, int e, int nbuck) {
  __shared__ int lh[256];
  int tid = threadIdx.x, blk = blockIdx.x;
  lh[tid] = 0;
  __syncthreads();
  int chunk = (e + gridDim.x - 1) / gridDim.x;
  int s = blk * chunk, en = min(e, s + chunk);
  for (int i = s + tid; i < en; i += 256) atomicAdd(&lh[dst[i] >> BSHIFT], 1);
  __syncthreads();
  if (tid < nbuck) cnt[tid * B1 + blk] = lh[tid];
}

__global__ __launch_bounds__(256) void scan1_kernel(const int* __restrict__ in,
    int* __restrict__ excl, int* __restrict__ bsum, int len) {
  __shared__ int s[256];
  int tid = threadIdx.x;
  int gid = blockIdx.x * 256 + tid;
  int v = gid < len ? in[gid] : 0;
  s[tid] = v;
  __syncthreads();
  for (int ofs = 1; ofs < 256; ofs <<= 1) {
    int t = (tid >= ofs) ? s[tid - ofs] : 0;
    __syncthreads();
    s[tid] += t;
    __syncthreads();
  }
  if (gid < len) excl[gid] = s[tid] - v;
  if (tid == 255) bsum[blockIdx.x] = s[255];
}

__global__ __launch_bounds__(1024) void scan2_kernel(int* __restrict__ bsum, int nb) {
  __shared__ int s[1024];
  int tid = threadIdx.x;
  int v = tid < nb ? bsum[tid] : 0;
  s[tid] = v;
  __syncthreads();
  for (int ofs = 1; ofs < 1024; ofs <<= 1) {
    int t = (tid >= ofs) ? s[tid - ofs] : 0;
    __syncthreads();
    s[tid] += t;
    __syncthreads();
  }
  if (tid < nb) bsum[tid] = s[tid] - v;  // exclusive
}

__global__ __launch_bounds__(256) void scan3_kernel(int* __restrict__ arr,
    const int* __restrict__ bsumx, int len) {
  int gid = blockIdx.x * 256 + threadIdx.x;
  if (gid < len) arr[gid] += bsumx[blockIdx.x];
}

__global__ __launch_bounds__(256) void binscatter_kernel(const int* __restrict__ src,
    const int* __restrict__ dst, const int* __restrict__ cntS,
    unsigned* __restrict__ binned, int e, int nbuck) {
  __shared__ int lcur[256];
  int tid = threadIdx.x, blk = blockIdx.x;
  if (tid < nbuck) lcur[tid] = cntS[tid * B1 + blk];
  __syncthreads();
  int chunk = (e + gridDim.x - 1) / gridDim.x;
  int s = blk * chunk, en = min(e, s + chunk);
  for (int i = s + tid; i < en; i += 256) {
    int d = dst[i];
    int pos = atomicAdd(&lcur[d >> BSHIFT], 1);
    binned[pos] = ((unsigned)(d & (BNODES - 1)) << 23) | (unsigned)src[i];
  }
}

__global__ __launch_bounds__(256) void bucket_csr_kernel(const unsigned* __restrict__ binned,
    const int* __restrict__ cntS, int* __restrict__ deg, int* __restrict__ off,
    int* __restrict__ csr, int e, int n, int nbuck) {
  int q = blockIdx.x, tid = threadIdx.x;
  int eBase = cntS[q * B1];
  int eEnd = (q + 1 < nbuck) ? cntS[(q + 1) * B1] : e;
  __shared__ int nh[BNODES], sc[BNODES], cu[BNODES];
  nh[tid] = 0; nh[tid + 256] = 0;
  __syncthreads();
  for (int i = eBase + tid; i < eEnd; i += 256) atomicAdd(&nh[binned[i] >> 23], 1);
  __syncthreads();
  sc[tid] = nh[tid]; sc[tid + 256] = nh[tid + 256];
  __syncthreads();
  for (int ofs = 1; ofs < BNODES; ofs <<= 1) {
    int a0 = sc[tid], a1 = sc[tid + 256];
    int b0 = (tid >= ofs) ? sc[tid - ofs] : 0;
    int b1 = (tid + 256 >= ofs) ? sc[tid + 256 - ofs] : 0;
    __syncthreads();
    sc[tid] = a0 + b0; sc[tid + 256] = a1 + b1;
    __syncthreads();
  }
  int e0 = sc[tid] - nh[tid], e1 = sc[tid + 256] - nh[tid + 256];
  cu[tid] = e0; cu[tid + 256] = e1;
  int node0 = q * BNODES + tid, node1 = node0 + 256;
  if (node0 < n) { deg[node0] = nh[tid];       off[node0] = eBase + e0; }
  if (node1 < n) { deg[node1] = nh[tid + 256]; off[node1] = eBase + e1; }
  __syncthreads();
  for (int i = eBase + tid; i < eEnd; i += 256) {
    unsigned v = binned[i];
    int pos = eBase + atomicAdd(&cu[v >> 23], 1);
    csr[pos] = (int)(v & 0x7FFFFF);
  }
}

// ---------- layer-1 aggregation: wave per node, SGPR-scalarized edge loop ----------
__global__ __launch_bounds__(256) void gat1_agg(const unsigned short* __restrict__ xw1,
    const float* __restrict__ al_src, const float* __restrict__ al_dst,
    const int* __restrict__ csr, const int* __restrict__ off, const int* __restrict__ deg,
    const float* __restrict__ b1, float* __restrict__ h1, int n) {
  const int node = rfl((int)((blockIdx.x * blockDim.x + threadIdx.x) >> 6));
  if (node >= n) return;
  const int lane = threadIdx.x & 63;
  const int h2 = lane >> 3;
  const int base = rfl(off[node]);
  const int cnt  = rfl(deg[node]);
  const float adst2 = al_dst[node * H1 + h2];
  const int* __restrict__ csrp = csr + base;

  float l = 0.f, acc = 0.f;

#define ON1(aj, xj) { \
    float sc = lrelu((aj) + adst2); \
    float p = __expf(sc); \
    acc += p * (xj); \
    l   += p; }

  int it = 0;
  for (; it + 8 <= cnt; it += 8) {
    int sL[8];
#pragma unroll
    for (int j = 0; j < 8; ++j) sL[j] = rfl(csrp[it + j]);   // -> s_load, SGPR
    float aL[8], xL[8];
#pragma unroll
    for (int j = 0; j < 8; ++j) aL[j] = al_src[sL[j] * H1 + h2];
#pragma unroll
    for (int j = 0; j < 8; ++j) xL[j] = bf2f(xw1[(size_t)sL[j] * F1 + lane]);
#pragma unroll
    for (int j = 0; j < 8; ++j) { ON1(aL[j], xL[j]); }
  }
  for (; it < cnt; ++it) {
    int s = rfl(csrp[it]);
    float av = al_src[s * H1 + h2];
    float xv = bf2f(xw1[(size_t)s * F1 + lane]);
    ON1(av, xv);
  }
  // self-loop
  {
    float av = al_src[node * H1 + h2];
    float xv = bf2f(xw1[(size_t)node * F1 + lane]);
    ON1(av, xv);
  }
#undef ON1

  float outv = acc / (l + 1e-16f) + b1[lane];
  h1[(size_t)node * F1 + lane] = outv > 0.f ? outv : __expf(outv) - 1.f;  // ELU
}

// ---------- GEMM2 + al2 fused: xw2[n,40] bf16, alS2/alD2 fp32 ----------
__global__ __launch_bounds__(256) void gemm2_kernel(const float* __restrict__ h1,
    const float* __restrict__ W2, const float* __restrict__ asrc,
    const float* __restrict__ adst, unsigned short* __restrict__ xw2,
    float* __restrict__ alS2, float* __restrict__ alD2, int n) {
  __shared__ float ws[F1 * C_OUT];
  __shared__ float wsa[C_OUT], wsd[C_OUT];
  int tid = threadIdx.x;
  for (int i = tid; i < F1 * C_OUT; i += 256) ws[i] = W2[i];
  if (tid < C_OUT) { wsa[tid] = asrc[tid]; wsd[tid] = adst[tid]; }
  __syncthreads();
  int node = blockIdx.x * 256 + tid;
  if (node >= n) return;
  const float4* row4 = (const float4*)(h1 + (size_t)node * F1);
  float acc[C_OUT];
#pragma unroll
  for (int j = 0; j < C_OUT; ++j) acc[j] = 0.f;
#pragma unroll 2
  for (int k4 = 0; k4 < 16; ++k4) {
    float4 xv = row4[k4];
    const float* w0 = &ws[(4 * k4 + 0) * C_OUT];
    const float* w1 = &ws[(4 * k4 + 1) * C_OUT];
    const float* w2 = &ws[(4 * k4 + 2) * C_OUT];
    const float* w3 = &ws[(4 * k4 + 3) * C_OUT];
#pragma unroll
    for (int j = 0; j < C_OUT; j += 4) {
      float4 v0 = *(const float4*)(w0 + j);
      float4 v1 = *(const float4*)(w1 + j);
      float4 v2 = *(const float4*)(w2 + j);
      float4 v3 = *(const float4*)(w3 + j);
      acc[j + 0] += xv.x * v0.x + xv.y * v1.x + xv.z * v2.x + xv.w * v3.x;
      acc[j + 1] += xv.x * v0.y + xv.y * v1.y + xv.z * v2.y + xv.w * v3.y;
      acc[j + 2] += xv.x * v0.z + xv.y * v1.z + xv.z * v2.z + xv.w * v3.z;
      acc[j + 3] += xv.x * v0.w + xv.y * v1.w + xv.z * v2.w + xv.w * v3.w;
    }
  }
  float s = 0.f, d = 0.f;
#pragma unroll
  for (int j = 0; j < C_OUT; ++j) { s += acc[j] * wsa[j]; d += acc[j] * wsd[j]; }
  alS2[node] = s;
  alD2[node] = d;
  unsigned short* orow = xw2 + (size_t)node * C_OUT;
#pragma unroll
  for (int j = 0; j < C_OUT; j += 4) {
    ushort4 o;
    o.x = f2bf(acc[j + 0]); o.y = f2bf(acc[j + 1]);
    o.z = f2bf(acc[j + 2]); o.w = f2bf(acc[j + 3]);
    *(ushort4*)(orow + j) = o;
  }
}

// ---------- layer-2 aggregation + log_softmax: wave per node, scalarized ----------
__global__ __launch_bounds__(256) void gat2_agg(const unsigned short* __restrict__ xw2,
    const float* __restrict__ al_src, const float* __restrict__ al_dst,
    const int* __restrict__ csr, const int* __restrict__ off, const int* __restrict__ deg,
    const float* __restrict__ b2, float* __restrict__ out, int n) {
  const int node = rfl((int)((blockIdx.x * blockDim.x + threadIdx.x) >> 6));
  if (node >= n) return;
  const int lane = threadIdx.x & 63;
  const int base = rfl(off[node]);
  const int cnt  = rfl(deg[node]);
  const float adst = al_dst[node];
  const bool act = lane < C_OUT;
  const int* __restrict__ csrp = csr + base;

  float l = 0.f, acc = 0.f;

#define ON2(aj, xj) { \
    float sc = lrelu((aj) + adst); \
    float p = __expf(sc); \
    acc += p * (xj); \
    l   += p; }

  int it = 0;
  for (; it + 8 <= cnt; it += 8) {
    int sL[8];
#pragma unroll
    for (int j = 0; j < 8; ++j) sL[j] = rfl(csrp[it + j]);   // -> s_load, SGPR
    float aL[8], xL[8];
#pragma unroll
    for (int j = 0; j < 8; ++j) aL[j] = al_src[sL[j]];       // uniform -> scalar path
#pragma unroll
    for (int j = 0; j < 8; ++j) xL[j] = act ? bf2f(xw2[(size_t)sL[j] * C_OUT + lane]) : 0.f;
#pragma unroll
    for (int j = 0; j < 8; ++j) { ON2(aL[j], xL[j]); }
  }
  for (; it < cnt; ++it) {
    int s = rfl(csrp[it]);
    float av = al_src[s];
    float xv = act ? bf2f(xw2[(size_t)s * C_OUT + lane]) : 0.f;
    ON2(av, xv);
  }
  // self-loop
  {
    float av = al_src[node];
    float xv = act ? bf2f(xw2[(size_t)node * C_OUT + lane]) : 0.f;
    ON2(av, xv);
  }
#undef ON2

  float val = act ? acc / (l + 1e-16f) + b2[lane] : -1e30f;
  float mx = val;
#pragma unroll
  for (int mask = 1; mask <= 32; mask <<= 1) mx = fmaxf(mx, __shfl_xor(mx, mask));
  float ex = act ? __expf(val - mx) : 0.f;
  float sum = ex;
#pragma unroll
  for (int mask = 1; mask <= 32; mask <<= 1) sum += __shfl_xor(sum, mask);
  if (act) out[(size_t)node * C_OUT + lane] = val - mx - __logf(sum);
}

extern "C" void kernel_launch(void* const* d_in, const int* in_sizes, int n_in,
                              void* d_out, int out_size, void* d_ws, size_t ws_size,
                              hipStream_t stream) {
  const float* x   = (const float*)d_in[0];
  const int*   ei  = (const int*)d_in[1];
  const float* W1  = (const float*)d_in[2];
  const float* as1 = (const float*)d_in[3];
  const float* ad1 = (const float*)d_in[4];
  const float* b1  = (const float*)d_in[5];
  const float* W2  = (const float*)d_in[6];
  const float* as2 = (const float*)d_in[7];
  const float* ad2 = (const float*)d_in[8];
  const float* b2  = (const float*)d_in[9];
  float* out = (float*)d_out;

  const int n = in_sizes[0] / F_IN;
  const int e = in_sizes[1] / 2;
  const int* srcIdx = ei;
  const int* dstIdx = ei + e;
  const int nbuck = (n + BNODES - 1) >> BSHIFT;   // <= 256 for n <= 128k
  const int clen = nbuck * B1;                    // flat counter array length

  char* p = (char*)d_ws;
  auto take = [&](size_t bytes) {
    char* q = p;
    p += (bytes + 255) & ~(size_t)255;
    return q;
  };
  unsigned short* xw1 = (unsigned short*)take((size_t)n * F1 * 2);
  float* h1           = (float*)take((size_t)n * F1 * 4);
  unsigned short* xw2 = (unsigned short*)take((size_t)n * C_OUT * 2);
  unsigned short* w1t = (unsigned short*)take((size_t)F_IN * F1 * 2);
  float* alS1 = (float*)take((size_t)n * H1 * 4);
  float* alD1 = (float*)take((size_t)n * H1 * 4);
  float* alS2 = (float*)take((size_t)n * 4);
  float* alD2 = (float*)take((size_t)n * 4);
  int* deg  = (int*)take((size_t)n * 4);
  int* offb = (int*)take((size_t)n * 4);
  int* cnt  = (int*)take((size_t)clen * 4);
  int* cntS = (int*)take((size_t)clen * 4);
  int* bsum = (int*)take(4096);
  unsigned* binned = (unsigned*)take((size_t)e * 4);
  int* csr  = (int*)take((size_t)e * 4);

  dim3 b256(256);
  w1cvt_kernel<<<dim3((F_IN * F1) / 256), b256, 0, stream>>>(W1, w1t);
  gemm1_mfma<<<dim3((n + 63) / 64), b256, 0, stream>>>(x, w1t, xw1, n);
  al1_kernel<<<dim3((n * H1 + 255) / 256), b256, 0, stream>>>(xw1, as1, ad1, alS1, alD1, n);

  binhist_kernel<<<dim3(B1), b256, 0, stream>>>(dstIdx, cnt, e, nbuck);
  int nbScan = (clen + 255) / 256;
  scan1_kernel<<<dim3(nbScan), b256, 0, stream>>>(cnt, cntS, bsum, clen);
  scan2_kernel<<<dim3(1), dim3(1024), 0, stream>>>(bsum, nbScan);
  scan3_kernel<<<dim3(nbScan), b256, 0, stream>>>(cntS, bsum, clen);
  binscatter_kernel<<<dim3(B1), b256, 0, stream>>>(srcIdx, dstIdx, cntS, binned, e, nbuck);
  bucket_csr_kernel<<<dim3(nbuck), b256, 0, stream>>>(binned, cntS, deg, offb, csr, e, n, nbuck);

  gat1_agg<<<dim3((n + 3) / 4), b256, 0, stream>>>(xw1, alS1, alD1, csr, offb, deg, b1, h1, n);
  gemm2_kernel<<<dim3((n + 255) / 256), b256, 0, stream>>>(h1, W2, as2, ad2, xw2, alS2, alD2, n);
  gat2_agg<<<dim3((n + 3) / 4), b256, 0, stream>>>(xw2, alS2, alD2, csr, offb, deg, b2, out, n);
}

// Round 7
// 470.459 us; speedup vs baseline: 2.8471x; 1.2583x over previous
//
#include <hip/hip_runtime.h>
#include <hip/hip_bf16.h>
#include <cstdint>
#include <cstddef>

#define F_IN 1024
#define F1 64
#define H1 8
#define C1 8
#define C_OUT 40
#define NEG 0.2f
#define LOG2E 1.442695040888963387f
#define B1 256          // blocks in bin/scatter phase
#define BSHIFT 9        // bucket = dst >> 9 (512 nodes per bucket)
#define BNODES 512

typedef __attribute__((ext_vector_type(8))) short short8;
typedef __attribute__((ext_vector_type(4))) float f32x4;

static __device__ __forceinline__ unsigned short f2bf(float f) {
  union { float f; unsigned u; } v; v.f = f;
  unsigned r = v.u + 0x7fff + ((v.u >> 16) & 1);  // RNE
  return (unsigned short)(r >> 16);
}
static __device__ __forceinline__ float bf2f(unsigned short h) {
  union { unsigned u; float f; } v; v.u = ((unsigned)h) << 16; return v.f;
}
// packed f32x2 -> bf16x2 (compiler emits v_cvt_pk_bf16_f32)
static __device__ __forceinline__ unsigned pkbf(float a, float b) {
  union { __hip_bfloat162 h; unsigned u; } c;
  c.h = __float22bfloat162_rn(float2{a, b});
  return c.u;
}
static __device__ __forceinline__ int rfl(int v) {
  return __builtin_amdgcn_readfirstlane(v);
}

// ---------- prep: W1T[64][1024] bf16 = transpose(W1[1024][64]) ----------
__global__ __launch_bounds__(256) void w1cvt_kernel(const float* __restrict__ W1,
                                                    unsigned short* __restrict__ w1t) {
  int i = blockIdx.x * 256 + threadIdx.x;           // 65536 total
  int c = i >> 10, k = i & 1023;
  w1t[i] = f2bf(W1[(size_t)k * F1 + c]);
}

// ---------- GEMM1 via MFMA, no LDS: xw1[n,64] = x[n,1024] @ W1, bf16 out ----------
__global__ __launch_bounds__(256) void gemm1_mfma(const float* __restrict__ x,
                                                  const unsigned short* __restrict__ w1t,
                                                  unsigned short* __restrict__ xw1, int n) {
  const int tid = threadIdx.x;
  const int wv = tid >> 6;          // wave 0..3 -> rows 16w..16w+15
  const int l = tid & 63;
  const int lr = l & 15;            // A row / B col / C col
  const int lg = l >> 4;            // k-group
  const int rowBase = blockIdx.x * 64 + wv * 16;
  int row = rowBase + lr;
  int rowc = row < n ? row : (n - 1);
  const float* px = x + (size_t)rowc * F_IN + lg * 8;

  f32x4 acc0 = {0.f, 0.f, 0.f, 0.f}, acc1 = acc0, acc2 = acc0, acc3 = acc0;

#pragma unroll 4
  for (int k0 = 0; k0 < F_IN; k0 += 32) {
    float4 xa = *(const float4*)(px + k0);
    float4 xb = *(const float4*)(px + k0 + 4);
    union { short8 s; unsigned u[4]; } af;
    af.u[0] = pkbf(xa.x, xa.y);
    af.u[1] = pkbf(xa.z, xa.w);
    af.u[2] = pkbf(xb.x, xb.y);
    af.u[3] = pkbf(xb.z, xb.w);
    const size_t kOff = (size_t)(k0 + lg * 8);
    short8 b0 = *(const short8*)(w1t + (size_t)(0 * 16 + lr) * F_IN + kOff);
    short8 b1 = *(const short8*)(w1t + (size_t)(1 * 16 + lr) * F_IN + kOff);
    short8 b2 = *(const short8*)(w1t + (size_t)(2 * 16 + lr) * F_IN + kOff);
    short8 b3 = *(const short8*)(w1t + (size_t)(3 * 16 + lr) * F_IN + kOff);
    acc0 = __builtin_amdgcn_mfma_f32_16x16x32_bf16(af.s, b0, acc0, 0, 0, 0);
    acc1 = __builtin_amdgcn_mfma_f32_16x16x32_bf16(af.s, b1, acc1, 0, 0, 0);
    acc2 = __builtin_amdgcn_mfma_f32_16x16x32_bf16(af.s, b2, acc2, 0, 0, 0);
    acc3 = __builtin_amdgcn_mfma_f32_16x16x32_bf16(af.s, b3, acc3, 0, 0, 0);
  }

  // C/D layout: col = lane&15, row = (lane>>4)*4 + reg   [m89-verified]
#pragma unroll
  for (int r = 0; r < 4; ++r) {
    int orow = rowBase + lg * 4 + r;
    if (orow < n) {
      unsigned short* po = xw1 + (size_t)orow * F1 + lr;
      po[0]  = f2bf(acc0[r]);
      po[16] = f2bf(acc1[r]);
      po[32] = f2bf(acc2[r]);
      po[48] = f2bf(acc3[r]);
    }
  }
}

// ---------- per-(node,head) attention logits, layer 1 (scaled by LOG2E) ----------
__global__ __launch_bounds__(256) void al1_kernel(const unsigned short* __restrict__ xw1,
    const float* __restrict__ asrc, const float* __restrict__ adst,
    float* __restrict__ al_src, float* __restrict__ al_dst, int n) {
  int id = blockIdx.x * 256 + threadIdx.x;
  if (id >= n * H1) return;
  int node = id >> 3, h = id & 7;
  const unsigned short* row = xw1 + (size_t)node * F1 + h * C1;
  float s = 0.f, d = 0.f;
#pragma unroll
  for (int c = 0; c < C1; ++c) {
    float v = bf2f(row[c]);
    s += v * asrc[h * C1 + c];
    d += v * adst[h * C1 + c];
  }
  al_src[id] = s * LOG2E;
  al_dst[id] = d * LOG2E;
}

// ---------- CSR build via 2-level counting sort ----------
__global__ __launch_bounds__(256) void binhist_kernel(const int* __restrict__ dst,
    int* __restrict__ cnt, int e, int nbuck) {
  __shared__ int lh[256];
  int tid = threadIdx.x, blk = blockIdx.x;
  lh[tid] = 0;
  __syncthreads();
  int chunk = (e + gridDim.x - 1) / gridDim.x;
  int s = blk * chunk, en = min(e, s + chunk);
  for (int i = s + tid; i < en; i += 256) atomicAdd(&lh[dst[i] >> BSHIFT], 1);
  __syncthreads();
  if (tid < nbuck) cnt[tid * B1 + blk] = lh[tid];
}

__global__ __launch_bounds__(256) void scan1_kernel(const int* __restrict__ in,
    int* __restrict__ excl, int* __restrict__ bsum, int len) {
  __shared__ int s[256];
  int tid = threadIdx.x;
  int gid = blockIdx.x * 256 + tid;
  int v = gid < len ? in[gid] : 0;
  s[tid] = v;
  __syncthreads();
  for (int ofs = 1; ofs < 256; ofs <<= 1) {
    int t = (tid >= ofs) ? s[tid - ofs] : 0;
    __syncthreads();
    s[tid] += t;
    __syncthreads();
  }
  if (gid < len) excl[gid] = s[tid] - v;
  if (tid == 255) bsum[blockIdx.x] = s[255];
}

__global__ __launch_bounds__(1024) void scan2_kernel(int* __restrict__ bsum, int nb) {
  __shared__ int s[1024];
  int tid = threadIdx.x;
  int v = tid < nb ? bsum[tid] : 0;
  s[tid] = v;
  __syncthreads();
  for (int ofs = 1; ofs < 1024; ofs <<= 1) {
    int t = (tid >= ofs) ? s[tid - ofs] : 0;
    __syncthreads();
    s[tid] += t;
    __syncthreads();
  }
  if (tid < nb) bsum[tid] = s[tid] - v;  // exclusive
}

// scan3 deleted: scan1 blocks align 1:1 with buckets, so global base of
// (bucket q, block b) = cntS[q*256+b] + bsum[q], and bucket bounds are bsum[q].

__global__ __launch_bounds__(256) void binscatter_kernel(const int* __restrict__ src,
    const int* __restrict__ dst, const int* __restrict__ cntS,
    const int* __restrict__ bsum, unsigned* __restrict__ binned, int e, int nbuck) {
  __shared__ int lcur[256];
  int tid = threadIdx.x, blk = blockIdx.x;
  if (tid < nbuck) lcur[tid] = cntS[tid * B1 + blk] + bsum[tid];
  __syncthreads();
  int chunk = (e + gridDim.x - 1) / gridDim.x;
  int s = blk * chunk, en = min(e, s + chunk);
  for (int i = s + tid; i < en; i += 256) {
    int d = dst[i];
    int pos = atomicAdd(&lcur[d >> BSHIFT], 1);
    binned[pos] = ((unsigned)(d & (BNODES - 1)) << 23) | (unsigned)src[i];
  }
}

__global__ __launch_bounds__(256) void bucket_csr_kernel(const unsigned* __restrict__ binned,
    const int* __restrict__ bsum, int* __restrict__ deg, int* __restrict__ off,
    int* __restrict__ csr, int e, int n, int nbuck) {
  int q = blockIdx.x, tid = threadIdx.x;
  int eBase = bsum[q];
  int eEnd = (q + 1 < nbuck) ? bsum[q + 1] : e;
  __shared__ int nh[BNODES], sc[BNODES], cu[BNODES];
  nh[tid] = 0; nh[tid + 256] = 0;
  __syncthreads();
  for (int i = eBase + tid; i < eEnd; i += 256) atomicAdd(&nh[binned[i] >> 23], 1);
  __syncthreads();
  sc[tid] = nh[tid]; sc[tid + 256] = nh[tid + 256];
  __syncthreads();
  for (int ofs = 1; ofs < BNODES; ofs <<= 1) {
    int a0 = sc[tid], a1 = sc[tid + 256];
    int b0 = (tid >= ofs) ? sc[tid - ofs] : 0;
    int b1 = (tid + 256 >= ofs) ? sc[tid + 256 - ofs] : 0;
    __syncthreads();
    sc[tid] = a0 + b0; sc[tid + 256] = a1 + b1;
    __syncthreads();
  }
  int e0 = sc[tid] - nh[tid], e1 = sc[tid + 256] - nh[tid + 256];
  cu[tid] = e0; cu[tid + 256] = e1;
  int node0 = q * BNODES + tid, node1 = node0 + 256;
  if (node0 < n) { deg[node0] = nh[tid];       off[node0] = eBase + e0; }
  if (node1 < n) { deg[node1] = nh[tid + 256]; off[node1] = eBase + e1; }
  __syncthreads();
  for (int i = eBase + tid; i < eEnd; i += 256) {
    unsigned v = binned[i];
    int pos = eBase + atomicAdd(&cu[v >> 23], 1);
    csr[pos] = (int)(v & 0x7FFFFF);
  }
}

// ---------- layer-1 aggregation: wave per node, 2 edges/iter, 2 ch/lane ----------
__global__ __launch_bounds__(256) void gat1_agg(const unsigned short* __restrict__ xw1,
    const float* __restrict__ al_src, const float* __restrict__ al_dst,
    const int* __restrict__ csr, const int* __restrict__ off, const int* __restrict__ deg,
    const float* __restrict__ b1, float* __restrict__ h1, int n) {
  const int node = rfl((int)((blockIdx.x * blockDim.x + threadIdx.x) >> 6));
  if (node >= n) return;
  const int lane = threadIdx.x & 63;
  const int half = lane >> 5;          // which edge of the pair
  const int c2 = lane & 31;            // channel pair: 2c2, 2c2+1
  const int h = c2 >> 2;               // head of this channel pair
  const int base = rfl(off[node]);
  const int cnt  = rfl(deg[node]);
  const float adst = al_dst[node * H1 + h];   // pre-scaled by LOG2E
  const int* __restrict__ csrp = csr + base;
  const char* xwB = (const char*)xw1;
  const char* alB = (const char*)al_src;
  const int cOff = c2 << 2;            // byte offset of u32 channel pair
  const int hOff = h << 2;

  float acc0 = 0.f, acc1 = 0.f, l = 0.f;

#define PAIR_BODY(wv_, av_) { \
    float t = (av_) + adst; \
    float sc = fmaxf(t, NEG * t); \
    float p = __builtin_amdgcn_exp2f(sc); \
    acc0 = fmaf(p, bf2f((unsigned short)((wv_) & 0xffffu)), acc0); \
    acc1 = fmaf(p, bf2f((unsigned short)((wv_) >> 16)), acc1); \
    l += p; }

  int it = 0;
  for (; it + 8 <= cnt; it += 8) {
    int xo[4];
#pragma unroll
    for (int jp = 0; jp < 4; ++jp) {
      int s0 = rfl(csrp[it + 2 * jp]) << 7;       // s*128 bytes, SGPR
      int s1 = rfl(csrp[it + 2 * jp + 1]) << 7;
      xo[jp] = half ? s1 : s0;                    // one cndmask
    }
    unsigned wv[4]; float av[4];
#pragma unroll
    for (int jp = 0; jp < 4; ++jp) {
      wv[jp] = *(const unsigned*)(xwB + xo[jp] + cOff);
      av[jp] = *(const float*)(alB + (xo[jp] >> 2) + hOff);   // s*32 + h*4
    }
#pragma unroll
    for (int jp = 0; jp < 4; ++jp) PAIR_BODY(wv[jp], av[jp]);
  }
  for (; it + 2 <= cnt; it += 2) {
    int s0 = rfl(csrp[it]) << 7;
    int s1 = rfl(csrp[it + 1]) << 7;
    int bs = half ? s1 : s0;
    unsigned w = *(const unsigned*)(xwB + bs + cOff);
    float av = *(const float*)(alB + (bs >> 2) + hOff);
    PAIR_BODY(w, av);
  }
  // final pair: (odd remainder edge, self) or (self, dummy)
  {
    const bool odd = (it < cnt);
    int sA = odd ? rfl(csrp[it]) : node;
    int bs = (half ? node : sA) << 7;
    unsigned w = *(const unsigned*)(xwB + bs + cOff);
    float av = *(const float*)(alB + (bs >> 2) + hOff);
    float t = av + adst;
    float sc = fmaxf(t, NEG * t);
    float p = __builtin_amdgcn_exp2f(sc);
    if (!odd && half) p = 0.f;     // dummy half
    acc0 = fmaf(p, bf2f((unsigned short)(w & 0xffffu)), acc0);
    acc1 = fmaf(p, bf2f((unsigned short)(w >> 16)), acc1);
    l += p;
  }
#undef PAIR_BODY

  acc0 += __shfl_xor(acc0, 32);
  acc1 += __shfl_xor(acc1, 32);
  l    += __shfl_xor(l, 32);
  if (half == 0) {
    float inv = 1.f / (l + 1e-16f);
    float2 bv = *(const float2*)(b1 + (c2 << 1));
    float o0 = acc0 * inv + bv.x;
    float o1 = acc1 * inv + bv.y;
    o0 = o0 > 0.f ? o0 : __expf(o0) - 1.f;   // ELU
    o1 = o1 > 0.f ? o1 : __expf(o1) - 1.f;
    *(float2*)(h1 + (size_t)node * F1 + (c2 << 1)) = make_float2(o0, o1);
  }
}

// ---------- GEMM2 + al2 fused: xw2[n,40] bf16, alS2/alD2 fp32 (scaled) ----------
__global__ __launch_bounds__(256) void gemm2_kernel(const float* __restrict__ h1,
    const float* __restrict__ W2, const float* __restrict__ asrc,
    const float* __restrict__ adst, unsigned short* __restrict__ xw2,
    float* __restrict__ alS2, float* __restrict__ alD2, int n) {
  __shared__ float ws[F1 * C_OUT];
  __shared__ float wsa[C_OUT], wsd[C_OUT];
  int tid = threadIdx.x;
  for (int i = tid; i < F1 * C_OUT; i += 256) ws[i] = W2[i];
  if (tid < C_OUT) { wsa[tid] = asrc[tid]; wsd[tid] = adst[tid]; }
  __syncthreads();
  int node = blockIdx.x * 256 + tid;
  if (node >= n) return;
  const float4* row4 = (const float4*)(h1 + (size_t)node * F1);
  float acc[C_OUT];
#pragma unroll
  for (int j = 0; j < C_OUT; ++j) acc[j] = 0.f;
#pragma unroll 2
  for (int k4 = 0; k4 < 16; ++k4) {
    float4 xv = row4[k4];
    const float* w0 = &ws[(4 * k4 + 0) * C_OUT];
    const float* w1 = &ws[(4 * k4 + 1) * C_OUT];
    const float* w2 = &ws[(4 * k4 + 2) * C_OUT];
    const float* w3 = &ws[(4 * k4 + 3) * C_OUT];
#pragma unroll
    for (int j = 0; j < C_OUT; j += 4) {
      float4 v0 = *(const float4*)(w0 + j);
      float4 v1 = *(const float4*)(w1 + j);
      float4 v2 = *(const float4*)(w2 + j);
      float4 v3 = *(const float4*)(w3 + j);
      acc[j + 0] += xv.x * v0.x + xv.y * v1.x + xv.z * v2.x + xv.w * v3.x;
      acc[j + 1] += xv.x * v0.y + xv.y * v1.y + xv.z * v2.y + xv.w * v3.y;
      acc[j + 2] += xv.x * v0.z + xv.y * v1.z + xv.z * v2.z + xv.w * v3.z;
      acc[j + 3] += xv.x * v0.w + xv.y * v1.w + xv.z * v2.w + xv.w * v3.w;
    }
  }
  float s = 0.f, d = 0.f;
#pragma unroll
  for (int j = 0; j < C_OUT; ++j) { s += acc[j] * wsa[j]; d += acc[j] * wsd[j]; }
  alS2[node] = s * LOG2E;
  alD2[node] = d * LOG2E;
  unsigned short* orow = xw2 + (size_t)node * C_OUT;
#pragma unroll
  for (int j = 0; j < C_OUT; j += 4) {
    ushort4 o;
    o.x = f2bf(acc[j + 0]); o.y = f2bf(acc[j + 1]);
    o.z = f2bf(acc[j + 2]); o.w = f2bf(acc[j + 3]);
    *(ushort4*)(orow + j) = o;
  }
}

// ---------- layer-2 aggregation + log_softmax: wave per node, 2 edges/iter ----------
__global__ __launch_bounds__(256) void gat2_agg(const unsigned short* __restrict__ xw2,
    const float* __restrict__ alS, const float* __restrict__ alD,
    const int* __restrict__ csr, const int* __restrict__ off, const int* __restrict__ deg,
    const float* __restrict__ b2, float* __restrict__ out, int n) {
  const int node = rfl((int)((blockIdx.x * blockDim.x + threadIdx.x) >> 6));
  if (node >= n) return;
  const int lane = threadIdx.x & 63;
  const int half = lane >> 5;
  const int c2 = lane & 31;            // channel pair 2c2,2c2+1 (active c2<20)
  const bool act = c2 < 20;
  const int c2r = act ? c2 : 0;
  const int base = rfl(off[node]);
  const int cnt  = rfl(deg[node]);
  const float adst = alD[node];        // pre-scaled by LOG2E
  const int* __restrict__ csrp = csr + base;
  const char* xwB = (const char*)xw2;
  const char* alB = (const char*)alS;
  const int cOff = c2r << 2;

  float acc0 = 0.f, acc1 = 0.f, l = 0.f;

#define PAIR_BODY2(wv_, av_) { \
    float t = (av_) + adst; \
    float sc = fmaxf(t, NEG * t); \
    float p = __builtin_amdgcn_exp2f(sc); \
    acc0 = fmaf(p, bf2f((unsigned short)((wv_) & 0xffffu)), acc0); \
    acc1 = fmaf(p, bf2f((unsigned short)((wv_) >> 16)), acc1); \
    l += p; }

  int it = 0;
  for (; it + 8 <= cnt; it += 8) {
    int xo[4], ao[4];
#pragma unroll
    for (int jp = 0; jp < 4; ++jp) {
      int s0 = rfl(csrp[it + 2 * jp]);
      int s1 = rfl(csrp[it + 2 * jp + 1]);
      xo[jp] = half ? s1 * 80 : s0 * 80;          // row byte offset (scalar mul + cndmask)
      ao[jp] = half ? (s1 << 2) : (s0 << 2);
    }
    unsigned wv[4]; float av[4];
#pragma unroll
    for (int jp = 0; jp < 4; ++jp) {
      wv[jp] = *(const unsigned*)(xwB + xo[jp] + cOff);
      av[jp] = *(const float*)(alB + ao[jp]);
    }
#pragma unroll
    for (int jp = 0; jp < 4; ++jp) PAIR_BODY2(wv[jp], av[jp]);
  }
  for (; it + 2 <= cnt; it += 2) {
    int s0 = rfl(csrp[it]);
    int s1 = rfl(csrp[it + 1]);
    int bs = half ? s1 : s0;
    unsigned w = *(const unsigned*)(xwB + bs * 80 + cOff);
    float av = *(const float*)(alB + (bs << 2));
    PAIR_BODY2(w, av);
  }
  {
    const bool odd = (it < cnt);
    int sA = odd ? rfl(csrp[it]) : node;
    int bs = half ? node : sA;
    unsigned w = *(const unsigned*)(xwB + bs * 80 + cOff);
    float av = *(const float*)(alB + (bs << 2));
    float t = av + adst;
    float sc = fmaxf(t, NEG * t);
    float p = __builtin_amdgcn_exp2f(sc);
    if (!odd && half) p = 0.f;
    acc0 = fmaf(p, bf2f((unsigned short)(w & 0xffffu)), acc0);
    acc1 = fmaf(p, bf2f((unsigned short)(w >> 16)), acc1);
    l += p;
  }
#undef PAIR_BODY2

  acc0 += __shfl_xor(acc0, 32);
  acc1 += __shfl_xor(acc1, 32);
  l    += __shfl_xor(l, 32);

  float inv = 1.f / (l + 1e-16f);
  float v0 = -1e30f, v1 = -1e30f;
  if (act) {
    float2 bv = *(const float2*)(b2 + (c2 << 1));
    v0 = acc0 * inv + bv.x;
    v1 = acc1 * inv + bv.y;
  }
  float mx = fmaxf(v0, v1);
#pragma unroll
  for (int mask = 1; mask <= 16; mask <<= 1) mx = fmaxf(mx, __shfl_xor(mx, mask));
  float e0 = act ? __expf(v0 - mx) : 0.f;
  float e1 = act ? __expf(v1 - mx) : 0.f;
  float sum = e0 + e1;
#pragma unroll
  for (int mask = 1; mask <= 16; mask <<= 1) sum += __shfl_xor(sum, mask);
  if (half == 0 && act) {
    float ls = __logf(sum);
    *(float2*)(out + (size_t)node * C_OUT + (c2 << 1)) =
        make_float2(v0 - mx - ls, v1 - mx - ls);
  }
}

extern "C" void kernel_launch(void* const* d_in, const int* in_sizes, int n_in,
                              void* d_out, int out_size, void* d_ws, size_t ws_size,
                              hipStream_t stream) {
  const float* x   = (const float*)d_in[0];
  const int*   ei  = (const int*)d_in[1];
  const float* W1  = (const float*)d_in[2];
  const float* as1 = (const float*)d_in[3];
  const float* ad1 = (const float*)d_in[4];
  const float* b1  = (const float*)d_in[5];
  const float* W2  = (const float*)d_in[6];
  const float* as2 = (const float*)d_in[7];
  const float* ad2 = (const float*)d_in[8];
  const float* b2  = (const float*)d_in[9];
  float* out = (float*)d_out;

  const int n = in_sizes[0] / F_IN;
  const int e = in_sizes[1] / 2;
  const int* srcIdx = ei;
  const int* dstIdx = ei + e;
  const int nbuck = (n + BNODES - 1) >> BSHIFT;   // <= 256 for n <= 128k
  const int clen = nbuck * B1;                    // flat counter array length

  char* p = (char*)d_ws;
  auto take = [&](size_t bytes) {
    char* q = p;
    p += (bytes + 255) & ~(size_t)255;
    return q;
  };
  unsigned short* xw1 = (unsigned short*)take((size_t)n * F1 * 2);
  float* h1           = (float*)take((size_t)n * F1 * 4);
  unsigned short* xw2 = (unsigned short*)take((size_t)n * C_OUT * 2);
  unsigned short* w1t = (unsigned short*)take((size_t)F_IN * F1 * 2);
  float* alS1 = (float*)take((size_t)n * H1 * 4);
  float* alD1 = (float*)take((size_t)n * H1 * 4);
  float* alS2 = (float*)take((size_t)n * 4);
  float* alD2 = (float*)take((size_t)n * 4);
  int* deg  = (int*)take((size_t)n * 4);
  int* offb = (int*)take((size_t)n * 4);
  int* cnt  = (int*)take((size_t)clen * 4);
  int* cntS = (int*)take((size_t)clen * 4);
  int* bsum = (int*)take(4096);
  unsigned* binned = (unsigned*)take((size_t)e * 4);
  int* csr  = (int*)take((size_t)e * 4);

  dim3 b256(256);
  w1cvt_kernel<<<dim3((F_IN * F1) / 256), b256, 0, stream>>>(W1, w1t);
  gemm1_mfma<<<dim3((n + 63) / 64), b256, 0, stream>>>(x, w1t, xw1, n);
  al1_kernel<<<dim3((n * H1 + 255) / 256), b256, 0, stream>>>(xw1, as1, ad1, alS1, alD1, n);

  binhist_kernel<<<dim3(B1), b256, 0, stream>>>(dstIdx, cnt, e, nbuck);
  int nbScan = (clen + 255) / 256;                // == nbuck
  scan1_kernel<<<dim3(nbScan), b256, 0, stream>>>(cnt, cntS, bsum, clen);
  scan2_kernel<<<dim3(1), dim3(1024), 0, stream>>>(bsum, nbScan);
  binscatter_kernel<<<dim3(B1), b256, 0, stream>>>(srcIdx, dstIdx, cntS, bsum, binned, e, nbuck);
  bucket_csr_kernel<<<dim3(nbuck), b256, 0, stream>>>(binned, bsum, deg, offb, csr, e, n, nbuck);

  gat1_agg<<<dim3((n + 3) / 4), b256, 0, stream>>>(xw1, alS1, alD1, csr, offb, deg, b1, h1, n);
  gemm2_kernel<<<dim3((n + 255) / 256), b256, 0, stream>>>(h1, W2, as2, ad2, xw2, alS2, alD2, n);
  gat2_agg<<<dim3((n + 3) / 4), b256, 0, stream>>>(xw2, alS2, alD2, csr, offb, deg, b2, out, n);
}